// Round 4
// baseline (1615.686 us; speedup 1.0000x reference)
//
#include <hip/hip_runtime.h>
#include <hip/hip_bf16.h>
#include <cstdint>
#include <cstddef>

#define BB   8
#define NN   4096
#define CC   64
#define KK   16
#define INCH 131
#define H2   128
#define NPOSF 524288.0f
#define BNEPS 1e-5f
#define FBIG 3.4e38f

// ---------- helpers ----------
__device__ __forceinline__ unsigned short f2bf(float x) {
  union { float f; unsigned u; } v; v.f = x;
  unsigned u = v.u;
  return (unsigned short)((u + 0x7fffu + ((u >> 16) & 1u)) >> 16);
}
__device__ __forceinline__ float bf2f(unsigned short h) {
  union { unsigned u; float f; } v; v.u = ((unsigned)h) << 16; return v.f;
}
__device__ __forceinline__ void store4bf(unsigned short* p, float4 v) {
  ushort4 u; u.x = f2bf(v.x); u.y = f2bf(v.y); u.z = f2bf(v.z); u.w = f2bf(v.w);
  *(ushort4*)p = u;
}

#define FMA4(acc, w4, s) { acc.x += w4.x*(s); acc.y += w4.y*(s); acc.z += w4.z*(s); acc.w += w4.w*(s); }

// ---------- utility kernels ----------
__global__ __launch_bounds__(256) void k_zero(float* p) {
  p[blockIdx.x * 256 + threadIdx.x] = 0.f;   // 16384 floats of stats
}

// pos2t[b][n] = (x,y,z, x^2+y^2+z^2) — arithmetic PINNED to np rounding (no fma contraction)
__global__ __launch_bounds__(256) void k_pos2t(const float* __restrict__ pos2, float4* __restrict__ out) {
  int i = blockIdx.x * 256 + threadIdx.x;
  int b = i >> 12, n = i & 4095;
  float x = pos2[(b*3 + 0)*NN + n];
  float y = pos2[(b*3 + 1)*NN + n];
  float z = pos2[(b*3 + 2)*NN + n];
  float w = __fadd_rn(__fadd_rn(__fmul_rn(x,x), __fmul_rn(y,y)), __fmul_rn(z,z));
  out[i] = make_float4(x, y, z, w);
}

// [B,64,N] -> [B,N,64]
__global__ __launch_bounds__(256) void k_transpose(const float* __restrict__ in, float* __restrict__ out) {
  __shared__ float tile[32][33];
  int b = blockIdx.z;
  int n0 = blockIdx.x * 32, c0 = blockIdx.y * 32;
  int tx = threadIdx.x, ty = threadIdx.y;
  #pragma unroll
  for (int i = 0; i < 32; i += 8)
    tile[ty + i][tx] = in[((size_t)(b*CC + c0 + ty + i))*NN + n0 + tx];
  __syncthreads();
  #pragma unroll
  for (int i = 0; i < 32; i += 8)
    out[((size_t)(b*NN + n0 + ty + i))*CC + c0 + tx] = tile[tx][ty + i];
}

// W -> Wt[c][o]
__global__ __launch_bounds__(256) void k_wt(const float* __restrict__ W0, const float* __restrict__ W1,
                                            const float* __restrict__ W2, float* __restrict__ Wt0,
                                            float* __restrict__ Wt1, float* __restrict__ Wt2) {
  int i = blockIdx.x * 256 + threadIdx.x;
  if (i < 8384) { int c = i >> 6, o = i & 63; Wt0[i] = W0[o*INCH + c]; }
  int j = i - 8384;
  if (j >= 0 && j < 4096) { int c = j >> 6, o = j & 63; Wt1[j] = W1[o*64 + c]; }
  int k2 = i - 12480;
  if (k2 >= 0 && k2 < 8192) { int c = k2 >> 7, o = k2 & 127; Wt2[k2] = W2[o*64 + c]; }
}

// ---------- KNN: 64 queries/block (lane=query), 4 CONTIGUOUS ref partitions (wave=partition) ----------
// Tie-exactness: partitions are index-contiguous ascending in wave id h, so the merge's
// prefer-lower-h on equal d == prefer-lower-index == np top_k tie-break. Distance arithmetic
// pinned with _rn intrinsics (sequential mul/add, numpy order) — immune to fma contraction.
__global__ __launch_bounds__(256) void k_knn(const float* __restrict__ pos1_re,
                                             const float4* __restrict__ pos2t,
                                             unsigned short* __restrict__ idxOut) {
  __shared__ float          mbd[64*4*16];   // [q][h][j] 16 KB
  __shared__ unsigned short mbi[64*4*16];   // 8 KB

  const int t = threadIdx.x;
  const int q = t & 63;
  const int h = __builtin_amdgcn_readfirstlane(t >> 6);   // wave-uniform partition id
  const int b = blockIdx.y;
  const int n = blockIdx.x * 64 + q;

  const float qx = pos1_re[(b*3 + 0)*NN + n];
  const float qy = pos1_re[(b*3 + 1)*NN + n];
  const float qz = pos1_re[(b*3 + 2)*NN + n];
  const float q2 = __fadd_rn(__fadd_rn(__fmul_rn(qx,qx), __fmul_rn(qy,qy)), __fmul_rn(qz,qz));

  float bd[KK]; int bi[KK];
  #pragma unroll
  for (int j = 0; j < KK; ++j) { bd[j] = FBIG; bi[j] = 0; }

  const float4* rp = pos2t + (size_t)b*NN + h*1024;   // wave-uniform base
  for (int i = 0; i < 1024; ++i) {
    float4 r = rp[i];                                  // uniform address -> broadcast
    float dot = __fadd_rn(__fadd_rn(__fmul_rn(qx,r.x), __fmul_rn(qy,r.y)), __fmul_rn(qz,r.z));
    float d   = __fsub_rn(__fadd_rn(q2, r.w), __fmul_rn(2.0f, dot));
    if (d < bd[KK-1]) {
      float cd = d; int ci = h*1024 + i;
      #pragma unroll
      for (int j = 0; j < KK; ++j) {
        const bool lt = cd < bd[j];
        const float od = bd[j]; const int oi = bi[j];
        bd[j] = lt ? cd : od;
        bi[j] = lt ? ci : oi;
        cd = lt ? od : cd;
        ci = lt ? oi : ci;
      }
    }
  }

  const int base = (q*4 + h)*16;
  #pragma unroll
  for (int j = 0; j < KK; ++j) { mbd[base + j] = bd[j]; mbi[base + j] = (unsigned short)bi[j]; }
  __syncthreads();

  if (h == 0) {
    const int mb = q*64;
    int p0 = 0, p1 = 0, p2 = 0, p3 = 0;
    float h0 = mbd[mb], h1 = mbd[mb+16], h2 = mbd[mb+32], h3 = mbd[mb+48];
    unsigned short* outp = idxOut + ((size_t)(b*NN + n))*KK;
    #pragma unroll
    for (int j = 0; j < KK; ++j) {
      bool a01 = h1 < h0; float d01 = a01 ? h1 : h0;   // tie -> h0 (lower indices)
      bool a23 = h3 < h2; float d23 = a23 ? h3 : h2;   // tie -> h2
      bool af = d23 < d01;                             // tie -> 01-group (lower)
      int sel = af ? (a23 ? 3 : 2) : (a01 ? 1 : 0);
      if (sel == 0)      { outp[j] = mbi[mb + p0];      ++p0; h0 = (p0 < 16) ? mbd[mb + p0]      : FBIG; }
      else if (sel == 1) { outp[j] = mbi[mb + 16 + p1]; ++p1; h1 = (p1 < 16) ? mbd[mb + 16 + p1] : FBIG; }
      else if (sel == 2) { outp[j] = mbi[mb + 32 + p2]; ++p2; h2 = (p2 < 16) ? mbd[mb + 32 + p2] : FBIG; }
      else               { outp[j] = mbi[mb + 48 + p3]; ++p3; h3 = (p3 < 16) ? mbd[mb + 48 + p3] : FBIG; }
    }
  }
}

// ---------- stats reduction macro ----------
#define RED4(A0_,A1_,A2_,A3_, comp, chidx) { \
  float s_ = A0_.comp + A1_.comp + A2_.comp + A3_.comp; \
  float q_ = A0_.comp*A0_.comp + A1_.comp*A1_.comp + A2_.comp*A2_.comp + A3_.comp*A3_.comp; \
  s_ += __shfl_xor(s_, 16); s_ += __shfl_xor(s_, 32); \
  q_ += __shfl_xor(q_, 16); q_ += __shfl_xor(q_, 32); \
  if (pg == 0) { atomicAdd(&sS[chidx], s_); atomicAdd(&sQ[chidx], q_); } \
}

// ---------- layer 0 ----------
__global__ __launch_bounds__(128) void k_layer0(
    const unsigned short* __restrict__ nidx, const float4* __restrict__ pos2t,
    const float* __restrict__ pos1, const float* __restrict__ f2t,
    const float* __restrict__ f1t, const float* __restrict__ Wt0,
    unsigned short* __restrict__ Y0, float* __restrict__ gS, float* __restrict__ gQ) {
  extern __shared__ float sm[];
  float* wsL = sm;                         // 131*64 = 8384
  float* xs  = sm + 8384;                  // 2*131*16 = 4192
  float* sS  = sm + 8384 + 4192;           // 64
  float* sQ  = sS + 64;                    // 64
  int*   mI  = (int*)(sQ + 64);            // 32

  const int t = threadIdx.x;
  const int b = blockIdx.y;
  const int n0 = blockIdx.x * 2;

  for (int i = t; i < 2096; i += 128) ((float4*)wsL)[i] = ((const float4*)Wt0)[i];
  sS[t] = 0.f;
  if (t < 32) mI[t] = (int)nidx[((size_t)(b*NN + n0 + (t >> 4)))*KK + (t & 15)];
  __syncthreads();

  const int w = t >> 6, lane = t & 63;
  const int kq = lane >> 2, cg = lane & 3;
  const int n = n0 + w;
  float* xw = xs + w*(INCH*16);
  {
    const int m = mI[w*16 + kq];
    const float* f2row = f2t + ((size_t)(b*NN + m))*64;
    const float* f1row = f1t + ((size_t)(b*NN + n))*64;
    #pragma unroll
    for (int it = 0; it < 4; ++it) {
      int c = it*16 + cg*4;
      float4 v2 = *(const float4*)(f2row + c);
      float4 v1 = *(const float4*)(f1row + c);
      xw[(3 + c + 0)*16 + kq] = v2.x;
      xw[(3 + c + 1)*16 + kq] = v2.y;
      xw[(3 + c + 2)*16 + kq] = v2.z;
      xw[(3 + c + 3)*16 + kq] = v2.w;
      xw[(67 + c + 0)*16 + kq] = v1.x;
      xw[(67 + c + 1)*16 + kq] = v1.y;
      xw[(67 + c + 2)*16 + kq] = v1.z;
      xw[(67 + c + 3)*16 + kq] = v1.w;
    }
    if (lane < 16) {
      float4 p = pos2t[(size_t)b*NN + mI[w*16 + lane]];
      float px = pos1[(b*3 + 0)*NN + n];
      float py = pos1[(b*3 + 1)*NN + n];
      float pz = pos1[(b*3 + 2)*NN + n];
      xw[0*16 + lane] = p.x - px;
      xw[1*16 + lane] = p.y - py;
      xw[2*16 + lane] = p.z - pz;
    }
  }
  __syncthreads();

  const int o4 = lane & 15, pg = lane >> 4;
  float4 a0 = {0,0,0,0}, a1 = {0,0,0,0}, a2 = {0,0,0,0}, a3 = {0,0,0,0};
  const float* wb = wsL + 4*o4;
  const float* xb = xw + 4*pg;
  #pragma unroll 4
  for (int c = 0; c < INCH; ++c) {
    float4 w4 = *(const float4*)(wb + c*64);
    float4 xv = *(const float4*)(xb + c*16);
    FMA4(a0, w4, xv.x); FMA4(a1, w4, xv.y); FMA4(a2, w4, xv.z); FMA4(a3, w4, xv.w);
  }
  {
    size_t basep = ((size_t)(b*NN + n))*KK;
    store4bf(Y0 + (basep + pg*4 + 0)*64 + 4*o4, a0);
    store4bf(Y0 + (basep + pg*4 + 1)*64 + 4*o4, a1);
    store4bf(Y0 + (basep + pg*4 + 2)*64 + 4*o4, a2);
    store4bf(Y0 + (basep + pg*4 + 3)*64 + 4*o4, a3);
  }
  RED4(a0,a1,a2,a3, x, 4*o4 + 0)
  RED4(a0,a1,a2,a3, y, 4*o4 + 1)
  RED4(a0,a1,a2,a3, z, 4*o4 + 2)
  RED4(a0,a1,a2,a3, w, 4*o4 + 3)
  __syncthreads();
  const int slot = blockIdx.x & 31;
  if (t < 64) { atomicAdd(&gS[slot*64 + t], sS[t]); atomicAdd(&gQ[slot*64 + t], sQ[t]); }
}

// ---------- finalize BN stats (sum 32 copies) ----------
__global__ __launch_bounds__(128) void k_finalize(const float* __restrict__ S, const float* __restrict__ Q,
                                                  const float* __restrict__ g, const float* __restrict__ bb_,
                                                  float* __restrict__ A, float* __restrict__ Bt, int ch) {
  int t = threadIdx.x;
  if (t < ch) {
    float s = 0.f, qq = 0.f;
    for (int c = 0; c < 32; ++c) { s += S[c*ch + t]; qq += Q[c*ch + t]; }
    float mean = s * (1.0f / NPOSF);
    float var  = qq * (1.0f / NPOSF) - mean*mean;
    float rs   = 1.0f / sqrtf(var + BNEPS);
    float a    = g[t] * rs;
    A[t] = a; Bt[t] = bb_[t] - mean*a;
  }
}

// ---------- layer 1 ----------
__global__ __launch_bounds__(256) void k_layer1(
    const unsigned short* __restrict__ Y0, const float* __restrict__ A0, const float* __restrict__ B0,
    const float* __restrict__ Wt1, unsigned short* __restrict__ Y1,
    float* __restrict__ gS, float* __restrict__ gQ) {
  extern __shared__ float sm[];
  float* wsL = sm;            // 4096
  float* xs  = sm + 4096;     // 4096
  float* aL  = sm + 8192;     // 64
  float* bL  = aL + 64;       // 64
  float* sS  = bL + 64;       // 64
  float* sQ  = sS + 64;       // 64

  const int t = threadIdx.x;
  const int b = blockIdx.y, n0 = blockIdx.x * 4;
  for (int i = t; i < 1024; i += 256) ((float4*)wsL)[i] = ((const float4*)Wt1)[i];
  if (t < 64)  { aL[t] = A0[t]; bL[t] = B0[t]; }
  if (t < 128) { sS[t] = 0.f; }
  __syncthreads();

  const int w = t >> 6, lane = t & 63, kq = lane >> 2, cg = lane & 3;
  const int n = n0 + w;
  float* xw = xs + w*1024;
  const unsigned short* yrow = Y0 + (((size_t)(b*NN + n))*KK + kq)*64;
  #pragma unroll
  for (int it = 0; it < 4; ++it) {
    int c = it*16 + cg*4;
    ushort4 u = *(const ushort4*)(yrow + c);
    xw[(c + 0)*16 + kq] = fmaxf(bf2f(u.x)*aL[c + 0] + bL[c + 0], 0.f);
    xw[(c + 1)*16 + kq] = fmaxf(bf2f(u.y)*aL[c + 1] + bL[c + 1], 0.f);
    xw[(c + 2)*16 + kq] = fmaxf(bf2f(u.z)*aL[c + 2] + bL[c + 2], 0.f);
    xw[(c + 3)*16 + kq] = fmaxf(bf2f(u.w)*aL[c + 3] + bL[c + 3], 0.f);
  }
  __syncthreads();

  const int o4 = lane & 15, pg = lane >> 4;
  float4 a0 = {0,0,0,0}, a1 = {0,0,0,0}, a2 = {0,0,0,0}, a3 = {0,0,0,0};
  const float* wb = wsL + 4*o4;
  const float* xb = xw + 4*pg;
  #pragma unroll 4
  for (int c = 0; c < 64; ++c) {
    float4 w4 = *(const float4*)(wb + c*64);
    float4 xv = *(const float4*)(xb + c*16);
    FMA4(a0, w4, xv.x); FMA4(a1, w4, xv.y); FMA4(a2, w4, xv.z); FMA4(a3, w4, xv.w);
  }
  {
    size_t basep = ((size_t)(b*NN + n))*KK;
    store4bf(Y1 + (basep + pg*4 + 0)*64 + 4*o4, a0);
    store4bf(Y1 + (basep + pg*4 + 1)*64 + 4*o4, a1);
    store4bf(Y1 + (basep + pg*4 + 2)*64 + 4*o4, a2);
    store4bf(Y1 + (basep + pg*4 + 3)*64 + 4*o4, a3);
  }
  RED4(a0,a1,a2,a3, x, 4*o4 + 0)
  RED4(a0,a1,a2,a3, y, 4*o4 + 1)
  RED4(a0,a1,a2,a3, z, 4*o4 + 2)
  RED4(a0,a1,a2,a3, w, 4*o4 + 3)
  __syncthreads();
  const int slot = blockIdx.x & 31;
  if (t < 64) { atomicAdd(&gS[slot*64 + t], sS[t]); atomicAdd(&gQ[slot*64 + t], sQ[t]); }
}

// ---------- layer 2 stats ----------
__global__ __launch_bounds__(256) void k_l2stats(
    const unsigned short* __restrict__ Y1, const float* __restrict__ A1, const float* __restrict__ B1,
    const float* __restrict__ Wt2, float* __restrict__ gS, float* __restrict__ gQ) {
  extern __shared__ float sm[];
  float* wsL = sm;            // 8192
  float* xs  = sm + 8192;     // 4096
  float* aL  = sm + 12288;    // 64
  float* bL  = aL + 64;       // 64
  float* sS  = bL + 64;       // 128
  float* sQ  = sS + 128;      // 128

  const int t = threadIdx.x;
  const int b = blockIdx.y, n0 = blockIdx.x * 4;
  for (int i = t; i < 2048; i += 256) ((float4*)wsL)[i] = ((const float4*)Wt2)[i];
  if (t < 64) { aL[t] = A1[t]; bL[t] = B1[t]; }
  sS[t] = 0.f;
  __syncthreads();

  const int w = t >> 6, lane = t & 63, kq = lane >> 2, cg = lane & 3;
  const int n = n0 + w;
  float* xw = xs + w*1024;
  const unsigned short* yrow = Y1 + (((size_t)(b*NN + n))*KK + kq)*64;
  #pragma unroll
  for (int it = 0; it < 4; ++it) {
    int c = it*16 + cg*4;
    ushort4 u = *(const ushort4*)(yrow + c);
    xw[(c + 0)*16 + kq] = fmaxf(bf2f(u.x)*aL[c + 0] + bL[c + 0], 0.f);
    xw[(c + 1)*16 + kq] = fmaxf(bf2f(u.y)*aL[c + 1] + bL[c + 1], 0.f);
    xw[(c + 2)*16 + kq] = fmaxf(bf2f(u.z)*aL[c + 2] + bL[c + 2], 0.f);
    xw[(c + 3)*16 + kq] = fmaxf(bf2f(u.w)*aL[c + 3] + bL[c + 3], 0.f);
  }
  __syncthreads();

  const int o4 = lane & 15, pg = lane >> 4;
  float4 c00={0,0,0,0},c01={0,0,0,0},c02={0,0,0,0},c03={0,0,0,0};
  float4 c10={0,0,0,0},c11={0,0,0,0},c12={0,0,0,0},c13={0,0,0,0};
  const float* wbA = wsL + 4*o4;
  const float* wbB = wsL + 64 + 4*o4;
  const float* xb  = xw + 4*pg;
  #pragma unroll 4
  for (int c = 0; c < 64; ++c) {
    float4 xv = *(const float4*)(xb + c*16);
    float4 wA = *(const float4*)(wbA + c*128);
    float4 wB = *(const float4*)(wbB + c*128);
    FMA4(c00, wA, xv.x); FMA4(c01, wA, xv.y); FMA4(c02, wA, xv.z); FMA4(c03, wA, xv.w);
    FMA4(c10, wB, xv.x); FMA4(c11, wB, xv.y); FMA4(c12, wB, xv.z); FMA4(c13, wB, xv.w);
  }
  RED4(c00,c01,c02,c03, x, 4*o4 + 0)
  RED4(c00,c01,c02,c03, y, 4*o4 + 1)
  RED4(c00,c01,c02,c03, z, 4*o4 + 2)
  RED4(c00,c01,c02,c03, w, 4*o4 + 3)
  RED4(c10,c11,c12,c13, x, 64 + 4*o4 + 0)
  RED4(c10,c11,c12,c13, y, 64 + 4*o4 + 1)
  RED4(c10,c11,c12,c13, z, 64 + 4*o4 + 2)
  RED4(c10,c11,c12,c13, w, 64 + 4*o4 + 3)
  __syncthreads();
  const int slot = blockIdx.x & 31;
  if (t < 128) { atomicAdd(&gS[slot*128 + t], sS[t]); atomicAdd(&gQ[slot*128 + t], sQ[t]); }
}

#define MAXC(A0_,A1_,A2_,A3_, comp, chidx) { \
  int ch_ = (chidx); float al_ = aL2[ch_], be_ = bL2[ch_]; \
  float m_ = fmaxf(al_*A0_.comp + be_, 0.f); \
  m_ = fmaxf(m_, fmaxf(al_*A1_.comp + be_, 0.f)); \
  m_ = fmaxf(m_, fmaxf(al_*A2_.comp + be_, 0.f)); \
  m_ = fmaxf(m_, fmaxf(al_*A3_.comp + be_, 0.f)); \
  m_ = fmaxf(m_, __shfl_xor(m_, 16)); m_ = fmaxf(m_, __shfl_xor(m_, 32)); \
  if (pg == 0) oBuf[w*128 + ch_] = m_; \
}

__global__ __launch_bounds__(256) void k_l2final(
    const unsigned short* __restrict__ Y1, const float* __restrict__ A1, const float* __restrict__ B1,
    const float* __restrict__ Wt2, const float* __restrict__ A2, const float* __restrict__ B2,
    float* __restrict__ outF) {
  extern __shared__ float sm[];
  float* wsL  = sm;            // 8192
  float* xs   = sm + 8192;     // 4096
  float* aL   = sm + 12288;    // 64
  float* bL   = aL + 64;       // 64
  float* aL2  = bL + 64;       // 128
  float* bL2  = aL2 + 128;     // 128
  float* oBuf = bL2 + 128;     // 512

  const int t = threadIdx.x;
  const int b = blockIdx.y, n0 = blockIdx.x * 4;
  for (int i = t; i < 2048; i += 256) ((float4*)wsL)[i] = ((const float4*)Wt2)[i];
  if (t < 64)  { aL[t] = A1[t]; bL[t] = B1[t]; }
  if (t < 128) { aL2[t] = A2[t]; bL2[t] = B2[t]; }
  __syncthreads();

  const int w = t >> 6, lane = t & 63, kq = lane >> 2, cg = lane & 3;
  const int n = n0 + w;
  float* xw = xs + w*1024;
  const unsigned short* yrow = Y1 + (((size_t)(b*NN + n))*KK + kq)*64;
  #pragma unroll
  for (int it = 0; it < 4; ++it) {
    int c = it*16 + cg*4;
    ushort4 u = *(const ushort4*)(yrow + c);
    xw[(c + 0)*16 + kq] = fmaxf(bf2f(u.x)*aL[c + 0] + bL[c + 0], 0.f);
    xw[(c + 1)*16 + kq] = fmaxf(bf2f(u.y)*aL[c + 1] + bL[c + 1], 0.f);
    xw[(c + 2)*16 + kq] = fmaxf(bf2f(u.z)*aL[c + 2] + bL[c + 2], 0.f);
    xw[(c + 3)*16 + kq] = fmaxf(bf2f(u.w)*aL[c + 3] + bL[c + 3], 0.f);
  }
  __syncthreads();

  const int o4 = lane & 15, pg = lane >> 4;
  float4 c00={0,0,0,0},c01={0,0,0,0},c02={0,0,0,0},c03={0,0,0,0};
  float4 c10={0,0,0,0},c11={0,0,0,0},c12={0,0,0,0},c13={0,0,0,0};
  const float* wbA = wsL + 4*o4;
  const float* wbB = wsL + 64 + 4*o4;
  const float* xb  = xw + 4*pg;
  #pragma unroll 4
  for (int c = 0; c < 64; ++c) {
    float4 xv = *(const float4*)(xb + c*16);
    float4 wA = *(const float4*)(wbA + c*128);
    float4 wB = *(const float4*)(wbB + c*128);
    FMA4(c00, wA, xv.x); FMA4(c01, wA, xv.y); FMA4(c02, wA, xv.z); FMA4(c03, wA, xv.w);
    FMA4(c10, wB, xv.x); FMA4(c11, wB, xv.y); FMA4(c12, wB, xv.z); FMA4(c13, wB, xv.w);
  }
  MAXC(c00,c01,c02,c03, x, 4*o4 + 0)
  MAXC(c00,c01,c02,c03, y, 4*o4 + 1)
  MAXC(c00,c01,c02,c03, z, 4*o4 + 2)
  MAXC(c00,c01,c02,c03, w, 4*o4 + 3)
  MAXC(c10,c11,c12,c13, x, 64 + 4*o4 + 0)
  MAXC(c10,c11,c12,c13, y, 64 + 4*o4 + 1)
  MAXC(c10,c11,c12,c13, z, 64 + 4*o4 + 2)
  MAXC(c10,c11,c12,c13, w, 64 + 4*o4 + 3)
  __syncthreads();
  #pragma unroll
  for (int e = t; e < 512; e += 256) {
    int ch = e >> 2, nl = e & 3;
    outF[((size_t)b*H2 + ch)*NN + n0 + nl] = oBuf[nl*128 + ch];
  }
}

// ---------- launch ----------
extern "C" void kernel_launch(void* const* d_in, const int* in_sizes, int n_in,
                              void* d_out, int out_size, void* d_ws, size_t ws_size,
                              hipStream_t stream) {
  const float* pos1    = (const float*)d_in[0];
  const float* pos1_re = (const float*)d_in[1];
  const float* pos2    = (const float*)d_in[2];
  const float* f1      = (const float*)d_in[3];
  const float* f2      = (const float*)d_in[4];
  const float* W0 = (const float*)d_in[6];
  const float* g0 = (const float*)d_in[7];
  const float* b0 = (const float*)d_in[8];
  const float* W1 = (const float*)d_in[9];
  const float* g1 = (const float*)d_in[10];
  const float* b1 = (const float*)d_in[11];
  const float* W2 = (const float*)d_in[12];
  const float* g2 = (const float*)d_in[13];
  const float* b2 = (const float*)d_in[14];
  float* out = (float*)d_out;

  // workspace layout (bytes)
  char* ws = (char*)d_ws;
  float* stats = (float*)ws;                 // 16384 floats @0 (65536 B)
  float* S0 = stats;         float* Q0 = stats + 2048;
  float* S1 = stats + 4096;  float* Q1 = stats + 6144;
  float* S2 = stats + 8192;  float* Q2 = stats + 12288;
  float* prm = (float*)(ws + 65536);         // 512 floats
  float* A0 = prm;       float* B0a = prm + 64;
  float* A1 = prm + 128; float* B1a = prm + 192;
  float* A2 = prm + 256; float* B2a = prm + 384;
  float* Wt0 = (float*)(ws + 67584);         // 8384 f
  float* Wt1 = (float*)(ws + 101120);        // 4096 f
  float* Wt2 = (float*)(ws + 117504);        // 8192 f -> ends 150272
  unsigned short* idxb = (unsigned short*)(ws + 150528);   // 1,048,576 B
  float4* pos2t = (float4*)(ws + 1199104);   // 524,288 B
  float*  f2t   = (float*)(ws + 1723392);    // 8 MB
  float*  f1t   = (float*)(ws + 10112000);   // 8 MB
  unsigned short* Y0 = (unsigned short*)(ws + 18500608);   // 64 MB
  unsigned short* Y1 = (unsigned short*)(ws + 85609472);   // 64 MB -> ends 152,718,336
  if (ws_size < 152718336u) return;

  k_zero<<<dim3(64), 256, 0, stream>>>(stats);
  k_wt<<<dim3(81), 256, 0, stream>>>(W0, W1, W2, Wt0, Wt1, Wt2);
  hipMemcpyAsync(out, pos1, (size_t)BB*3*NN*sizeof(float), hipMemcpyDeviceToDevice, stream);

  k_pos2t<<<dim3(BB*NN/256), 256, 0, stream>>>(pos2, pos2t);
  k_transpose<<<dim3(NN/32, CC/32, BB), dim3(32, 8), 0, stream>>>(f2, f2t);
  k_transpose<<<dim3(NN/32, CC/32, BB), dim3(32, 8), 0, stream>>>(f1, f1t);
  k_knn<<<dim3(NN/64, BB), 256, 0, stream>>>(pos1_re, pos2t, idxb);

  k_layer0<<<dim3(NN/2, BB), 128, 12736*4, stream>>>(idxb, pos2t, pos1, f2t, f1t, Wt0, Y0, S0, Q0);
  k_finalize<<<1, 128, 0, stream>>>(S0, Q0, g0, b0, A0, B0a, 64);

  k_layer1<<<dim3(NN/4, BB), 256, 8448*4, stream>>>(Y0, A0, B0a, Wt1, Y1, S1, Q1);
  k_finalize<<<1, 128, 0, stream>>>(S1, Q1, g1, b1, A1, B1a, 64);

  k_l2stats<<<dim3(NN/4, BB), 256, 12672*4, stream>>>(Y1, A1, B1a, Wt2, S2, Q2);
  k_finalize<<<1, 128, 0, stream>>>(S2, Q2, g2, b2, A2, B2a, 128);

  k_l2final<<<dim3(NN/4, BB), 256, 13184*4, stream>>>(Y1, A1, B1a, Wt2, A2, B2a, out + (size_t)BB*3*NN);
}

// Round 5
// 1370.514 us; speedup vs baseline: 1.1789x; 1.1789x over previous
//
#include <hip/hip_runtime.h>
#include <hip/hip_bf16.h>
#include <cstdint>
#include <cstddef>

#define BB   8
#define NN   4096
#define CC   64
#define KK   16
#define INCH 131
#define H2   128
#define NPOSF 524288.0f
#define BNEPS 1e-5f
#define FBIG 3.4e38f
#define PARTS 8
#define PSZ   512   // NN / PARTS

// ---------- helpers ----------
__device__ __forceinline__ unsigned short f2bf(float x) {
  union { float f; unsigned u; } v; v.f = x;
  unsigned u = v.u;
  return (unsigned short)((u + 0x7fffu + ((u >> 16) & 1u)) >> 16);
}
__device__ __forceinline__ float bf2f(unsigned short h) {
  union { unsigned u; float f; } v; v.u = ((unsigned)h) << 16; return v.f;
}
__device__ __forceinline__ void store4bf(unsigned short* p, float4 v) {
  ushort4 u; u.x = f2bf(v.x); u.y = f2bf(v.y); u.z = f2bf(v.z); u.w = f2bf(v.w);
  *(ushort4*)p = u;
}

#define FMA4(acc, w4, s) { acc.x += w4.x*(s); acc.y += w4.y*(s); acc.z += w4.z*(s); acc.w += w4.w*(s); }

// ---------- utility kernels ----------
__global__ __launch_bounds__(256) void k_zero(float* p) {
  p[blockIdx.x * 256 + threadIdx.x] = 0.f;   // 16384 floats of stats
}

// pos2t[b][n] = (x,y,z, x^2+y^2+z^2) — arithmetic PINNED to np rounding (no fma contraction)
__global__ __launch_bounds__(256) void k_pos2t(const float* __restrict__ pos2, float4* __restrict__ out) {
  int i = blockIdx.x * 256 + threadIdx.x;
  int b = i >> 12, n = i & 4095;
  float x = pos2[(b*3 + 0)*NN + n];
  float y = pos2[(b*3 + 1)*NN + n];
  float z = pos2[(b*3 + 2)*NN + n];
  float w = __fadd_rn(__fadd_rn(__fmul_rn(x,x), __fmul_rn(y,y)), __fmul_rn(z,z));
  out[i] = make_float4(x, y, z, w);
}

// [B,64,N] -> [B,N,64]
__global__ __launch_bounds__(256) void k_transpose(const float* __restrict__ in, float* __restrict__ out) {
  __shared__ float tile[32][33];
  int b = blockIdx.z;
  int n0 = blockIdx.x * 32, c0 = blockIdx.y * 32;
  int tx = threadIdx.x, ty = threadIdx.y;
  #pragma unroll
  for (int i = 0; i < 32; i += 8)
    tile[ty + i][tx] = in[((size_t)(b*CC + c0 + ty + i))*NN + n0 + tx];
  __syncthreads();
  #pragma unroll
  for (int i = 0; i < 32; i += 8)
    out[((size_t)(b*NN + n0 + ty + i))*CC + c0 + tx] = tile[tx][ty + i];
}

// W -> Wt[c][o]
__global__ __launch_bounds__(256) void k_wt(const float* __restrict__ W0, const float* __restrict__ W1,
                                            const float* __restrict__ W2, float* __restrict__ Wt0,
                                            float* __restrict__ Wt1, float* __restrict__ Wt2) {
  int i = blockIdx.x * 256 + threadIdx.x;
  if (i < 8384) { int c = i >> 6, o = i & 63; Wt0[i] = W0[o*INCH + c]; }
  int j = i - 8384;
  if (j >= 0 && j < 4096) { int c = j >> 6, o = j & 63; Wt1[j] = W1[o*64 + c]; }
  int k2 = i - 12480;
  if (k2 >= 0 && k2 < 8192) { int c = k2 >> 7, o = k2 & 127; Wt2[k2] = W2[o*64 + c]; }
}

// ---------- KNN: 64 queries/block (lane=query), 8 CONTIGUOUS ref partitions (wave=partition) ----------
// Tie-exactness (HW-validated in R4): contiguous partitions ascending in wave id, every merge
// level prefers the lower-range list on equal d == prefer-lower-index == np top_k tie-break.
// Distance arithmetic pinned with _rn intrinsics — immune to fma contraction.
// LDS layout [list][j][q]: lane-consecutive -> 2 lanes/bank (conflict-free, m136).
#define KNN_PROC(r, ii) { \
  float dot = __fadd_rn(__fadd_rn(__fmul_rn(qx,(r).x), __fmul_rn(qy,(r).y)), __fmul_rn(qz,(r).z)); \
  float d   = __fsub_rn(__fadd_rn(q2, (r).w), __fmul_rn(2.0f, dot)); \
  if (d < bd[KK-1]) { \
    float cd = d; int ci = (ii); \
    _Pragma("unroll") \
    for (int j = 0; j < KK; ++j) { \
      const bool lt = cd < bd[j]; \
      const float od = bd[j]; const int oi = bi[j]; \
      bd[j] = lt ? cd : od; \
      bi[j] = lt ? ci : oi; \
      cd = lt ? od : cd; \
      ci = lt ? oi : ci; \
    } \
  } }

__global__ __launch_bounds__(512) void k_knn(const float* __restrict__ pos1_re,
                                             const float4* __restrict__ pos2t,
                                             unsigned short* __restrict__ idxOut) {
  __shared__ float          mbd[PARTS*16*64];   // [h][j][q] 32 KB
  __shared__ unsigned short mbi[PARTS*16*64];   // 16 KB

  const int t = threadIdx.x;
  const int q = t & 63;
  const int h = __builtin_amdgcn_readfirstlane(t >> 6);   // wave-uniform partition id
  const int b = blockIdx.y;
  const int n = blockIdx.x * 64 + q;

  const float qx = pos1_re[(b*3 + 0)*NN + n];
  const float qy = pos1_re[(b*3 + 1)*NN + n];
  const float qz = pos1_re[(b*3 + 2)*NN + n];
  const float q2 = __fadd_rn(__fadd_rn(__fmul_rn(qx,qx), __fmul_rn(qy,qy)), __fmul_rn(qz,qz));

  float bd[KK]; int bi[KK];
  #pragma unroll
  for (int j = 0; j < KK; ++j) { bd[j] = FBIG; bi[j] = 0; }

  const float4* rp = pos2t + (size_t)b*NN + h*PSZ;   // wave-uniform base
  const int ib = h*PSZ;
  for (int i0 = 0; i0 < PSZ; i0 += 4) {
    // batch-4 prefetch: 4 independent loads per waitcnt
    float4 r0 = rp[i0 + 0];
    float4 r1 = rp[i0 + 1];
    float4 r2 = rp[i0 + 2];
    float4 r3 = rp[i0 + 3];
    KNN_PROC(r0, ib + i0 + 0)
    KNN_PROC(r1, ib + i0 + 1)
    KNN_PROC(r2, ib + i0 + 2)
    KNN_PROC(r3, ib + i0 + 3)
  }

  #pragma unroll
  for (int j = 0; j < KK; ++j) {
    mbd[(h*16 + j)*64 + q] = bd[j];
    mbi[(h*16 + j)*64 + q] = (unsigned short)bi[j];
  }
  __syncthreads();

  // stage 1: waves 0..3 merge adjacent pair (2h, 2h+1) -> registers (static j index)
  float md_r[16]; unsigned short mi_r[16];
  if (h < 4) {
    const int rA = (2*h)*16, rB = rA + 16;
    int pA = 0, pB = 0;
    float dA = mbd[rA*64 + q], dB = mbd[rB*64 + q];
    unsigned short iA = mbi[rA*64 + q], iB = mbi[rB*64 + q];
    #pragma unroll
    for (int j = 0; j < 16; ++j) {
      bool tB = dB < dA;                    // tie -> A (lower-index range)
      md_r[j] = tB ? dB : dA;
      mi_r[j] = tB ? iB : iA;
      if (tB) { ++pB; if (pB < 16) { dB = mbd[(rB+pB)*64 + q]; iB = mbi[(rB+pB)*64 + q]; } else dB = FBIG; }
      else    { ++pA; if (pA < 16) { dA = mbd[(rA+pA)*64 + q]; iA = mbi[(rA+pA)*64 + q]; } else dA = FBIG; }
    }
  }
  __syncthreads();
  if (h < 4) {
    #pragma unroll
    for (int j = 0; j < 16; ++j) {
      mbd[(h*16 + j)*64 + q] = md_r[j];
      mbi[(h*16 + j)*64 + q] = mi_r[j];
    }
  }
  __syncthreads();

  // stage 2: wave 0, 4-way tournament over four contiguous 1024-ranges (R4-validated)
  if (h == 0) {
    int p0 = 0, p1 = 0, p2 = 0, p3 = 0;
    float e0 = mbd[ 0*64 + q], e1 = mbd[16*64 + q], e2 = mbd[32*64 + q], e3 = mbd[48*64 + q];
    unsigned short v0 = mbi[ 0*64 + q], v1 = mbi[16*64 + q], v2 = mbi[32*64 + q], v3 = mbi[48*64 + q];
    unsigned short* outp = idxOut + ((size_t)(b*NN + n))*KK;
    #pragma unroll
    for (int j = 0; j < KK; ++j) {
      bool a01 = e1 < e0; float d01 = a01 ? e1 : e0;   // tie -> list0 (lower indices)
      bool a23 = e3 < e2; float d23 = a23 ? e3 : e2;   // tie -> list2
      bool af = d23 < d01;                             // tie -> 01-group (lower)
      int sel = af ? (a23 ? 3 : 2) : (a01 ? 1 : 0);
      if (sel == 0)      { outp[j] = v0; ++p0; if (p0 < 16) { e0 = mbd[( 0+p0)*64+q]; v0 = mbi[( 0+p0)*64+q]; } else e0 = FBIG; }
      else if (sel == 1) { outp[j] = v1; ++p1; if (p1 < 16) { e1 = mbd[(16+p1)*64+q]; v1 = mbi[(16+p1)*64+q]; } else e1 = FBIG; }
      else if (sel == 2) { outp[j] = v2; ++p2; if (p2 < 16) { e2 = mbd[(32+p2)*64+q]; v2 = mbi[(32+p2)*64+q]; } else e2 = FBIG; }
      else               { outp[j] = v3; ++p3; if (p3 < 16) { e3 = mbd[(48+p3)*64+q]; v3 = mbi[(48+p3)*64+q]; } else e3 = FBIG; }
    }
  }
}

// ---------- stats reduction macro ----------
#define RED4(A0_,A1_,A2_,A3_, comp, chidx) { \
  float s_ = A0_.comp + A1_.comp + A2_.comp + A3_.comp; \
  float q_ = A0_.comp*A0_.comp + A1_.comp*A1_.comp + A2_.comp*A2_.comp + A3_.comp*A3_.comp; \
  s_ += __shfl_xor(s_, 16); s_ += __shfl_xor(s_, 32); \
  q_ += __shfl_xor(q_, 16); q_ += __shfl_xor(q_, 32); \
  if (pg == 0) { atomicAdd(&sS[chidx], s_); atomicAdd(&sQ[chidx], q_); } \
}

// ---------- layer 0 ----------
__global__ __launch_bounds__(128) void k_layer0(
    const unsigned short* __restrict__ nidx, const float4* __restrict__ pos2t,
    const float* __restrict__ pos1, const float* __restrict__ f2t,
    const float* __restrict__ f1t, const float* __restrict__ Wt0,
    unsigned short* __restrict__ Y0, float* __restrict__ gS, float* __restrict__ gQ) {
  extern __shared__ float sm[];
  float* wsL = sm;                         // 131*64 = 8384
  float* xs  = sm + 8384;                  // 2*131*16 = 4192
  float* sS  = sm + 8384 + 4192;           // 64
  float* sQ  = sS + 64;                    // 64
  int*   mI  = (int*)(sQ + 64);            // 32

  const int t = threadIdx.x;
  const int b = blockIdx.y;
  const int n0 = blockIdx.x * 2;

  for (int i = t; i < 2096; i += 128) ((float4*)wsL)[i] = ((const float4*)Wt0)[i];
  sS[t] = 0.f;
  if (t < 32) mI[t] = (int)nidx[((size_t)(b*NN + n0 + (t >> 4)))*KK + (t & 15)];
  __syncthreads();

  const int w = t >> 6, lane = t & 63;
  const int kq = lane >> 2, cg = lane & 3;
  const int n = n0 + w;
  float* xw = xs + w*(INCH*16);
  {
    const int m = mI[w*16 + kq];
    const float* f2row = f2t + ((size_t)(b*NN + m))*64;
    const float* f1row = f1t + ((size_t)(b*NN + n))*64;
    #pragma unroll
    for (int it = 0; it < 4; ++it) {
      int c = it*16 + cg*4;
      float4 v2 = *(const float4*)(f2row + c);
      float4 v1 = *(const float4*)(f1row + c);
      xw[(3 + c + 0)*16 + kq] = v2.x;
      xw[(3 + c + 1)*16 + kq] = v2.y;
      xw[(3 + c + 2)*16 + kq] = v2.z;
      xw[(3 + c + 3)*16 + kq] = v2.w;
      xw[(67 + c + 0)*16 + kq] = v1.x;
      xw[(67 + c + 1)*16 + kq] = v1.y;
      xw[(67 + c + 2)*16 + kq] = v1.z;
      xw[(67 + c + 3)*16 + kq] = v1.w;
    }
    if (lane < 16) {
      float4 p = pos2t[(size_t)b*NN + mI[w*16 + lane]];
      float px = pos1[(b*3 + 0)*NN + n];
      float py = pos1[(b*3 + 1)*NN + n];
      float pz = pos1[(b*3 + 2)*NN + n];
      xw[0*16 + lane] = p.x - px;
      xw[1*16 + lane] = p.y - py;
      xw[2*16 + lane] = p.z - pz;
    }
  }
  __syncthreads();

  const int o4 = lane & 15, pg = lane >> 4;
  float4 a0 = {0,0,0,0}, a1 = {0,0,0,0}, a2 = {0,0,0,0}, a3 = {0,0,0,0};
  const float* wb = wsL + 4*o4;
  const float* xb = xw + 4*pg;
  #pragma unroll 4
  for (int c = 0; c < INCH; ++c) {
    float4 w4 = *(const float4*)(wb + c*64);
    float4 xv = *(const float4*)(xb + c*16);
    FMA4(a0, w4, xv.x); FMA4(a1, w4, xv.y); FMA4(a2, w4, xv.z); FMA4(a3, w4, xv.w);
  }
  {
    size_t basep = ((size_t)(b*NN + n))*KK;
    store4bf(Y0 + (basep + pg*4 + 0)*64 + 4*o4, a0);
    store4bf(Y0 + (basep + pg*4 + 1)*64 + 4*o4, a1);
    store4bf(Y0 + (basep + pg*4 + 2)*64 + 4*o4, a2);
    store4bf(Y0 + (basep + pg*4 + 3)*64 + 4*o4, a3);
  }
  RED4(a0,a1,a2,a3, x, 4*o4 + 0)
  RED4(a0,a1,a2,a3, y, 4*o4 + 1)
  RED4(a0,a1,a2,a3, z, 4*o4 + 2)
  RED4(a0,a1,a2,a3, w, 4*o4 + 3)
  __syncthreads();
  const int slot = blockIdx.x & 31;
  if (t < 64) { atomicAdd(&gS[slot*64 + t], sS[t]); atomicAdd(&gQ[slot*64 + t], sQ[t]); }
}

// ---------- finalize BN stats (sum 32 copies) ----------
__global__ __launch_bounds__(128) void k_finalize(const float* __restrict__ S, const float* __restrict__ Q,
                                                  const float* __restrict__ g, const float* __restrict__ bb_,
                                                  float* __restrict__ A, float* __restrict__ Bt, int ch) {
  int t = threadIdx.x;
  if (t < ch) {
    float s = 0.f, qq = 0.f;
    for (int c = 0; c < 32; ++c) { s += S[c*ch + t]; qq += Q[c*ch + t]; }
    float mean = s * (1.0f / NPOSF);
    float var  = qq * (1.0f / NPOSF) - mean*mean;
    float rs   = 1.0f / sqrtf(var + BNEPS);
    float a    = g[t] * rs;
    A[t] = a; Bt[t] = bb_[t] - mean*a;
  }
}

// ---------- layer 1 ----------
__global__ __launch_bounds__(256) void k_layer1(
    const unsigned short* __restrict__ Y0, const float* __restrict__ A0, const float* __restrict__ B0,
    const float* __restrict__ Wt1, unsigned short* __restrict__ Y1,
    float* __restrict__ gS, float* __restrict__ gQ) {
  extern __shared__ float sm[];
  float* wsL = sm;            // 4096
  float* xs  = sm + 4096;     // 4096
  float* aL  = sm + 8192;     // 64
  float* bL  = aL + 64;       // 64
  float* sS  = bL + 64;       // 64
  float* sQ  = sS + 64;       // 64

  const int t = threadIdx.x;
  const int b = blockIdx.y, n0 = blockIdx.x * 4;
  for (int i = t; i < 1024; i += 256) ((float4*)wsL)[i] = ((const float4*)Wt1)[i];
  if (t < 64)  { aL[t] = A0[t]; bL[t] = B0[t]; }
  if (t < 128) { sS[t] = 0.f; }
  __syncthreads();

  const int w = t >> 6, lane = t & 63, kq = lane >> 2, cg = lane & 3;
  const int n = n0 + w;
  float* xw = xs + w*1024;
  const unsigned short* yrow = Y0 + (((size_t)(b*NN + n))*KK + kq)*64;
  #pragma unroll
  for (int it = 0; it < 4; ++it) {
    int c = it*16 + cg*4;
    ushort4 u = *(const ushort4*)(yrow + c);
    xw[(c + 0)*16 + kq] = fmaxf(bf2f(u.x)*aL[c + 0] + bL[c + 0], 0.f);
    xw[(c + 1)*16 + kq] = fmaxf(bf2f(u.y)*aL[c + 1] + bL[c + 1], 0.f);
    xw[(c + 2)*16 + kq] = fmaxf(bf2f(u.z)*aL[c + 2] + bL[c + 2], 0.f);
    xw[(c + 3)*16 + kq] = fmaxf(bf2f(u.w)*aL[c + 3] + bL[c + 3], 0.f);
  }
  __syncthreads();

  const int o4 = lane & 15, pg = lane >> 4;
  float4 a0 = {0,0,0,0}, a1 = {0,0,0,0}, a2 = {0,0,0,0}, a3 = {0,0,0,0};
  const float* wb = wsL + 4*o4;
  const float* xb = xw + 4*pg;
  #pragma unroll 4
  for (int c = 0; c < 64; ++c) {
    float4 w4 = *(const float4*)(wb + c*64);
    float4 xv = *(const float4*)(xb + c*16);
    FMA4(a0, w4, xv.x); FMA4(a1, w4, xv.y); FMA4(a2, w4, xv.z); FMA4(a3, w4, xv.w);
  }
  {
    size_t basep = ((size_t)(b*NN + n))*KK;
    store4bf(Y1 + (basep + pg*4 + 0)*64 + 4*o4, a0);
    store4bf(Y1 + (basep + pg*4 + 1)*64 + 4*o4, a1);
    store4bf(Y1 + (basep + pg*4 + 2)*64 + 4*o4, a2);
    store4bf(Y1 + (basep + pg*4 + 3)*64 + 4*o4, a3);
  }
  RED4(a0,a1,a2,a3, x, 4*o4 + 0)
  RED4(a0,a1,a2,a3, y, 4*o4 + 1)
  RED4(a0,a1,a2,a3, z, 4*o4 + 2)
  RED4(a0,a1,a2,a3, w, 4*o4 + 3)
  __syncthreads();
  const int slot = blockIdx.x & 31;
  if (t < 64) { atomicAdd(&gS[slot*64 + t], sS[t]); atomicAdd(&gQ[slot*64 + t], sQ[t]); }
}

// ---------- layer 2 stats ----------
__global__ __launch_bounds__(256) void k_l2stats(
    const unsigned short* __restrict__ Y1, const float* __restrict__ A1, const float* __restrict__ B1,
    const float* __restrict__ Wt2, float* __restrict__ gS, float* __restrict__ gQ) {
  extern __shared__ float sm[];
  float* wsL = sm;            // 8192
  float* xs  = sm + 8192;     // 4096
  float* aL  = sm + 12288;    // 64
  float* bL  = aL + 64;       // 64
  float* sS  = bL + 64;       // 128
  float* sQ  = sS + 128;      // 128

  const int t = threadIdx.x;
  const int b = blockIdx.y, n0 = blockIdx.x * 4;
  for (int i = t; i < 2048; i += 256) ((float4*)wsL)[i] = ((const float4*)Wt2)[i];
  if (t < 64) { aL[t] = A1[t]; bL[t] = B1[t]; }
  sS[t] = 0.f;
  __syncthreads();

  const int w = t >> 6, lane = t & 63, kq = lane >> 2, cg = lane & 3;
  const int n = n0 + w;
  float* xw = xs + w*1024;
  const unsigned short* yrow = Y1 + (((size_t)(b*NN + n))*KK + kq)*64;
  #pragma unroll
  for (int it = 0; it < 4; ++it) {
    int c = it*16 + cg*4;
    ushort4 u = *(const ushort4*)(yrow + c);
    xw[(c + 0)*16 + kq] = fmaxf(bf2f(u.x)*aL[c + 0] + bL[c + 0], 0.f);
    xw[(c + 1)*16 + kq] = fmaxf(bf2f(u.y)*aL[c + 1] + bL[c + 1], 0.f);
    xw[(c + 2)*16 + kq] = fmaxf(bf2f(u.z)*aL[c + 2] + bL[c + 2], 0.f);
    xw[(c + 3)*16 + kq] = fmaxf(bf2f(u.w)*aL[c + 3] + bL[c + 3], 0.f);
  }
  __syncthreads();

  const int o4 = lane & 15, pg = lane >> 4;
  float4 c00={0,0,0,0},c01={0,0,0,0},c02={0,0,0,0},c03={0,0,0,0};
  float4 c10={0,0,0,0},c11={0,0,0,0},c12={0,0,0,0},c13={0,0,0,0};
  const float* wbA = wsL + 4*o4;
  const float* wbB = wsL + 64 + 4*o4;
  const float* xb  = xw + 4*pg;
  #pragma unroll 4
  for (int c = 0; c < 64; ++c) {
    float4 xv = *(const float4*)(xb + c*16);
    float4 wA = *(const float4*)(wbA + c*128);
    float4 wB = *(const float4*)(wbB + c*128);
    FMA4(c00, wA, xv.x); FMA4(c01, wA, xv.y); FMA4(c02, wA, xv.z); FMA4(c03, wA, xv.w);
    FMA4(c10, wB, xv.x); FMA4(c11, wB, xv.y); FMA4(c12, wB, xv.z); FMA4(c13, wB, xv.w);
  }
  RED4(c00,c01,c02,c03, x, 4*o4 + 0)
  RED4(c00,c01,c02,c03, y, 4*o4 + 1)
  RED4(c00,c01,c02,c03, z, 4*o4 + 2)
  RED4(c00,c01,c02,c03, w, 4*o4 + 3)
  RED4(c10,c11,c12,c13, x, 64 + 4*o4 + 0)
  RED4(c10,c11,c12,c13, y, 64 + 4*o4 + 1)
  RED4(c10,c11,c12,c13, z, 64 + 4*o4 + 2)
  RED4(c10,c11,c12,c13, w, 64 + 4*o4 + 3)
  __syncthreads();
  const int slot = blockIdx.x & 31;
  if (t < 128) { atomicAdd(&gS[slot*128 + t], sS[t]); atomicAdd(&gQ[slot*128 + t], sQ[t]); }
}

#define MAXC(A0_,A1_,A2_,A3_, comp, chidx) { \
  int ch_ = (chidx); float al_ = aL2[ch_], be_ = bL2[ch_]; \
  float m_ = fmaxf(al_*A0_.comp + be_, 0.f); \
  m_ = fmaxf(m_, fmaxf(al_*A1_.comp + be_, 0.f)); \
  m_ = fmaxf(m_, fmaxf(al_*A2_.comp + be_, 0.f)); \
  m_ = fmaxf(m_, fmaxf(al_*A3_.comp + be_, 0.f)); \
  m_ = fmaxf(m_, __shfl_xor(m_, 16)); m_ = fmaxf(m_, __shfl_xor(m_, 32)); \
  if (pg == 0) oBuf[w*128 + ch_] = m_; \
}

__global__ __launch_bounds__(256) void k_l2final(
    const unsigned short* __restrict__ Y1, const float* __restrict__ A1, const float* __restrict__ B1,
    const float* __restrict__ Wt2, const float* __restrict__ A2, const float* __restrict__ B2,
    float* __restrict__ outF) {
  extern __shared__ float sm[];
  float* wsL  = sm;            // 8192
  float* xs   = sm + 8192;     // 4096
  float* aL   = sm + 12288;    // 64
  float* bL   = aL + 64;       // 64
  float* aL2  = bL + 64;       // 128
  float* bL2  = aL2 + 128;     // 128
  float* oBuf = bL2 + 128;     // 512

  const int t = threadIdx.x;
  const int b = blockIdx.y, n0 = blockIdx.x * 4;
  for (int i = t; i < 2048; i += 256) ((float4*)wsL)[i] = ((const float4*)Wt2)[i];
  if (t < 64)  { aL[t] = A1[t]; bL[t] = B1[t]; }
  if (t < 128) { aL2[t] = A2[t]; bL2[t] = B2[t]; }
  __syncthreads();

  const int w = t >> 6, lane = t & 63, kq = lane >> 2, cg = lane & 3;
  const int n = n0 + w;
  float* xw = xs + w*1024;
  const unsigned short* yrow = Y1 + (((size_t)(b*NN + n))*KK + kq)*64;
  #pragma unroll
  for (int it = 0; it < 4; ++it) {
    int c = it*16 + cg*4;
    ushort4 u = *(const ushort4*)(yrow + c);
    xw[(c + 0)*16 + kq] = fmaxf(bf2f(u.x)*aL[c + 0] + bL[c + 0], 0.f);
    xw[(c + 1)*16 + kq] = fmaxf(bf2f(u.y)*aL[c + 1] + bL[c + 1], 0.f);
    xw[(c + 2)*16 + kq] = fmaxf(bf2f(u.z)*aL[c + 2] + bL[c + 2], 0.f);
    xw[(c + 3)*16 + kq] = fmaxf(bf2f(u.w)*aL[c + 3] + bL[c + 3], 0.f);
  }
  __syncthreads();

  const int o4 = lane & 15, pg = lane >> 4;
  float4 c00={0,0,0,0},c01={0,0,0,0},c02={0,0,0,0},c03={0,0,0,0};
  float4 c10={0,0,0,0},c11={0,0,0,0},c12={0,0,0,0},c13={0,0,0,0};
  const float* wbA = wsL + 4*o4;
  const float* wbB = wsL + 64 + 4*o4;
  const float* xb  = xw + 4*pg;
  #pragma unroll 4
  for (int c = 0; c < 64; ++c) {
    float4 xv = *(const float4*)(xb + c*16);
    float4 wA = *(const float4*)(wbA + c*128);
    float4 wB = *(const float4*)(wbB + c*128);
    FMA4(c00, wA, xv.x); FMA4(c01, wA, xv.y); FMA4(c02, wA, xv.z); FMA4(c03, wA, xv.w);
    FMA4(c10, wB, xv.x); FMA4(c11, wB, xv.y); FMA4(c12, wB, xv.z); FMA4(c13, wB, xv.w);
  }
  MAXC(c00,c01,c02,c03, x, 4*o4 + 0)
  MAXC(c00,c01,c02,c03, y, 4*o4 + 1)
  MAXC(c00,c01,c02,c03, z, 4*o4 + 2)
  MAXC(c00,c01,c02,c03, w, 4*o4 + 3)
  MAXC(c10,c11,c12,c13, x, 64 + 4*o4 + 0)
  MAXC(c10,c11,c12,c13, y, 64 + 4*o4 + 1)
  MAXC(c10,c11,c12,c13, z, 64 + 4*o4 + 2)
  MAXC(c10,c11,c12,c13, w, 64 + 4*o4 + 3)
  __syncthreads();
  #pragma unroll
  for (int e = t; e < 512; e += 256) {
    int ch = e >> 2, nl = e & 3;
    outF[((size_t)b*H2 + ch)*NN + n0 + nl] = oBuf[nl*128 + ch];
  }
}

// ---------- launch ----------
extern "C" void kernel_launch(void* const* d_in, const int* in_sizes, int n_in,
                              void* d_out, int out_size, void* d_ws, size_t ws_size,
                              hipStream_t stream) {
  const float* pos1    = (const float*)d_in[0];
  const float* pos1_re = (const float*)d_in[1];
  const float* pos2    = (const float*)d_in[2];
  const float* f1      = (const float*)d_in[3];
  const float* f2      = (const float*)d_in[4];
  const float* W0 = (const float*)d_in[6];
  const float* g0 = (const float*)d_in[7];
  const float* b0 = (const float*)d_in[8];
  const float* W1 = (const float*)d_in[9];
  const float* g1 = (const float*)d_in[10];
  const float* b1 = (const float*)d_in[11];
  const float* W2 = (const float*)d_in[12];
  const float* g2 = (const float*)d_in[13];
  const float* b2 = (const float*)d_in[14];
  float* out = (float*)d_out;

  // workspace layout (bytes)
  char* ws = (char*)d_ws;
  float* stats = (float*)ws;                 // 16384 floats @0 (65536 B)
  float* S0 = stats;         float* Q0 = stats + 2048;
  float* S1 = stats + 4096;  float* Q1 = stats + 6144;
  float* S2 = stats + 8192;  float* Q2 = stats + 12288;
  float* prm = (float*)(ws + 65536);         // 512 floats
  float* A0 = prm;       float* B0a = prm + 64;
  float* A1 = prm + 128; float* B1a = prm + 192;
  float* A2 = prm + 256; float* B2a = prm + 384;
  float* Wt0 = (float*)(ws + 67584);         // 8384 f
  float* Wt1 = (float*)(ws + 101120);        // 4096 f
  float* Wt2 = (float*)(ws + 117504);        // 8192 f -> ends 150272
  unsigned short* idxb = (unsigned short*)(ws + 150528);   // 1,048,576 B
  float4* pos2t = (float4*)(ws + 1199104);   // 524,288 B
  float*  f2t   = (float*)(ws + 1723392);    // 8 MB
  float*  f1t   = (float*)(ws + 10112000);   // 8 MB
  unsigned short* Y0 = (unsigned short*)(ws + 18500608);   // 64 MB
  unsigned short* Y1 = (unsigned short*)(ws + 85609472);   // 64 MB -> ends 152,718,336
  if (ws_size < 152718336u) return;

  k_zero<<<dim3(64), 256, 0, stream>>>(stats);
  k_wt<<<dim3(81), 256, 0, stream>>>(W0, W1, W2, Wt0, Wt1, Wt2);
  hipMemcpyAsync(out, pos1, (size_t)BB*3*NN*sizeof(float), hipMemcpyDeviceToDevice, stream);

  k_pos2t<<<dim3(BB*NN/256), 256, 0, stream>>>(pos2, pos2t);
  k_transpose<<<dim3(NN/32, CC/32, BB), dim3(32, 8), 0, stream>>>(f2, f2t);
  k_transpose<<<dim3(NN/32, CC/32, BB), dim3(32, 8), 0, stream>>>(f1, f1t);
  k_knn<<<dim3(NN/64, BB), 512, 0, stream>>>(pos1_re, pos2t, idxb);

  k_layer0<<<dim3(NN/2, BB), 128, 12736*4, stream>>>(idxb, pos2t, pos1, f2t, f1t, Wt0, Y0, S0, Q0);
  k_finalize<<<1, 128, 0, stream>>>(S0, Q0, g0, b0, A0, B0a, 64);

  k_layer1<<<dim3(NN/4, BB), 256, 8448*4, stream>>>(Y0, A0, B0a, Wt1, Y1, S1, Q1);
  k_finalize<<<1, 128, 0, stream>>>(S1, Q1, g1, b1, A1, B1a, 64);

  k_l2stats<<<dim3(NN/4, BB), 256, 12672*4, stream>>>(Y1, A1, B1a, Wt2, S2, Q2);
  k_finalize<<<1, 128, 0, stream>>>(S2, Q2, g2, b2, A2, B2a, 128);

  k_l2final<<<dim3(NN/4, BB), 256, 13184*4, stream>>>(Y1, A1, B1a, Wt2, A2, B2a, out + (size_t)BB*3*NN);
}

// Round 6
// 838.402 us; speedup vs baseline: 1.9271x; 1.6347x over previous
//
#include <hip/hip_runtime.h>
#include <hip/hip_bf16.h>
#include <cstdint>
#include <cstddef>

#define BB   8
#define NN   4096
#define CC   64
#define KK   16
#define INCH 131
#define H2   128
#define NPOSF 524288.0f
#define BNEPS 1e-5f
#define FBIG 3.4e38f

// ---------- helpers ----------
__device__ __forceinline__ unsigned short f2bf(float x) {
  union { float f; unsigned u; } v; v.f = x;
  unsigned u = v.u;
  return (unsigned short)((u + 0x7fffu + ((u >> 16) & 1u)) >> 16);
}
__device__ __forceinline__ float bf2f(unsigned short h) {
  union { unsigned u; float f; } v; v.u = ((unsigned)h) << 16; return v.f;
}
__device__ __forceinline__ void store4bf(unsigned short* p, float4 v) {
  ushort4 u; u.x = f2bf(v.x); u.y = f2bf(v.y); u.z = f2bf(v.z); u.w = f2bf(v.w);
  *(ushort4*)p = u;
}

#define FMA4(acc, w4, s) { acc.x += w4.x*(s); acc.y += w4.y*(s); acc.z += w4.z*(s); acc.w += w4.w*(s); }

// ---------- utility kernels ----------
__global__ __launch_bounds__(256) void k_zero(float* p) {
  p[blockIdx.x * 256 + threadIdx.x] = 0.f;   // 16384 floats of stats
}

// pos2t[b][n] = (x,y,z, x^2+y^2+z^2) — arithmetic PINNED to np rounding (no fma contraction)
__global__ __launch_bounds__(256) void k_pos2t(const float* __restrict__ pos2, float4* __restrict__ out) {
  int i = blockIdx.x * 256 + threadIdx.x;
  int b = i >> 12, n = i & 4095;
  float x = pos2[(b*3 + 0)*NN + n];
  float y = pos2[(b*3 + 1)*NN + n];
  float z = pos2[(b*3 + 2)*NN + n];
  float w = __fadd_rn(__fadd_rn(__fmul_rn(x,x), __fmul_rn(y,y)), __fmul_rn(z,z));
  out[i] = make_float4(x, y, z, w);
}

// [B,64,N] -> [B,N,64]
__global__ __launch_bounds__(256) void k_transpose(const float* __restrict__ in, float* __restrict__ out) {
  __shared__ float tile[32][33];
  int b = blockIdx.z;
  int n0 = blockIdx.x * 32, c0 = blockIdx.y * 32;
  int tx = threadIdx.x, ty = threadIdx.y;
  #pragma unroll
  for (int i = 0; i < 32; i += 8)
    tile[ty + i][tx] = in[((size_t)(b*CC + c0 + ty + i))*NN + n0 + tx];
  __syncthreads();
  #pragma unroll
  for (int i = 0; i < 32; i += 8)
    out[((size_t)(b*NN + n0 + ty + i))*CC + c0 + tx] = tile[tx][ty + i];
}

// W -> Wt[c][o]
__global__ __launch_bounds__(256) void k_wt(const float* __restrict__ W0, const float* __restrict__ W1,
                                            const float* __restrict__ W2, float* __restrict__ Wt0,
                                            float* __restrict__ Wt1, float* __restrict__ Wt2) {
  int i = blockIdx.x * 256 + threadIdx.x;
  if (i < 8384) { int c = i >> 6, o = i & 63; Wt0[i] = W0[o*INCH + c]; }
  int j = i - 8384;
  if (j >= 0 && j < 4096) { int c = j >> 6, o = j & 63; Wt1[j] = W1[o*64 + c]; }
  int k2 = i - 12480;
  if (k2 >= 0 && k2 < 8192) { int c = k2 >> 7, o = k2 & 127; Wt2[k2] = W2[o*64 + c]; }
}

// ---------- KNN: wave-per-query, lane-distributed sorted top-16 ----------
// Only the neighbor SET must match np.top_k (downstream is sum/max over k —
// permutation-invariant). The set is decided by exact-fp32 distance comparisons
// (pinned _rn arithmetic, identical to np op order) with lower-index tie-break:
//  - candidates processed in ascending ref index (lane order via ffs);
//  - strict < vs current 16th rejects equal-d later indices;
//  - strict > shift places equal-d later indices after earlier ones.
// Top-16 sorted list lives one element per lane (lanes 0..15); insertion is a
// DPP row_shr:1 shift + select (~10 VALU, position-independent).
__global__ __launch_bounds__(512) void k_knn(const float* __restrict__ pos1_re,
                                             const float4* __restrict__ pos2t,
                                             unsigned short* __restrict__ idxOut) {
  const int lane = threadIdx.x & 63;
  const int wv   = threadIdx.x >> 6;          // 0..7
  const int b = blockIdx.y;
  const int n = blockIdx.x * 8 + wv;          // query id

  const float qx = pos1_re[(b*3 + 0)*NN + n];
  const float qy = pos1_re[(b*3 + 1)*NN + n];
  const float qz = pos1_re[(b*3 + 2)*NN + n];
  const float q2 = __fadd_rn(__fadd_rn(__fmul_rn(qx,qx), __fmul_rn(qy,qy)), __fmul_rn(qz,qz));

  unsigned bd  = 0xFFFFFFFFu;   // lane j (j<16): rank-j key (transformed distance)
  unsigned bix = 0u;            // lane j (j<16): rank-j ref index
  unsigned tau = 0xFFFFFFFFu;   // key of current 16th (rank 15)

  const float4* rp = pos2t + (size_t)b*NN;
  for (int it = 0; it < 64; ++it) {
    float4 r = rp[it*64 + lane];
    float dot = __fadd_rn(__fadd_rn(__fmul_rn(qx,r.x), __fmul_rn(qy,r.y)), __fmul_rn(qz,r.z));
    float d   = __fsub_rn(__fadd_rn(q2, r.w), __fmul_rn(2.0f, dot));
    unsigned du = __float_as_uint(d);
    du ^= (du >> 31) ? 0xFFFFFFFFu : 0x80000000u;   // exact total-order transform

    unsigned long long mask = __ballot(du < tau);
    while (mask) {
      const int l = __ffsll((unsigned long long)mask) - 1;
      mask &= (mask - 1);
      const unsigned sd = (unsigned)__builtin_amdgcn_readlane((int)du, l);
      if (sd >= tau) continue;                      // tau shrank since ballot
      const unsigned sidx = (unsigned)(it*64 + l);
      // wave-parallel sorted insert (lanes 0..15)
      int m = (bd > sd) ? 1 : 0;                    // strict: equal-d keeps earlier index first
      int pm = __builtin_amdgcn_update_dpp(0, m, 0x111, 0xF, 0xF, true);
      unsigned sb = (unsigned)__builtin_amdgcn_update_dpp(0, (int)bd,  0x111, 0xF, 0xF, true);
      unsigned si = (unsigned)__builtin_amdgcn_update_dpp(0, (int)bix, 0x111, 0xF, 0xF, true);
      if (m) { bd = pm ? sb : sd; bix = pm ? si : sidx; }
      tau = (unsigned)__builtin_amdgcn_readlane((int)bd, 15);
    }
  }

  if (lane < 16) {
    idxOut[((size_t)(b*NN + n))*KK + lane] = (unsigned short)bix;
  }
}

// ---------- stats reduction macro ----------
#define RED4(A0_,A1_,A2_,A3_, comp, chidx) { \
  float s_ = A0_.comp + A1_.comp + A2_.comp + A3_.comp; \
  float q_ = A0_.comp*A0_.comp + A1_.comp*A1_.comp + A2_.comp*A2_.comp + A3_.comp*A3_.comp; \
  s_ += __shfl_xor(s_, 16); s_ += __shfl_xor(s_, 32); \
  q_ += __shfl_xor(q_, 16); q_ += __shfl_xor(q_, 32); \
  if (pg == 0) { atomicAdd(&sS[chidx], s_); atomicAdd(&sQ[chidx], q_); } \
}

// ---------- layer 0 ----------
__global__ __launch_bounds__(128) void k_layer0(
    const unsigned short* __restrict__ nidx, const float4* __restrict__ pos2t,
    const float* __restrict__ pos1, const float* __restrict__ f2t,
    const float* __restrict__ f1t, const float* __restrict__ Wt0,
    unsigned short* __restrict__ Y0, float* __restrict__ gS, float* __restrict__ gQ) {
  extern __shared__ float sm[];
  float* wsL = sm;                         // 131*64 = 8384
  float* xs  = sm + 8384;                  // 2*131*16 = 4192
  float* sS  = sm + 8384 + 4192;           // 64
  float* sQ  = sS + 64;                    // 64
  int*   mI  = (int*)(sQ + 64);            // 32

  const int t = threadIdx.x;
  const int b = blockIdx.y;
  const int n0 = blockIdx.x * 2;

  for (int i = t; i < 2096; i += 128) ((float4*)wsL)[i] = ((const float4*)Wt0)[i];
  sS[t] = 0.f;
  if (t < 32) mI[t] = (int)nidx[((size_t)(b*NN + n0 + (t >> 4)))*KK + (t & 15)];
  __syncthreads();

  const int w = t >> 6, lane = t & 63;
  const int kq = lane >> 2, cg = lane & 3;
  const int n = n0 + w;
  float* xw = xs + w*(INCH*16);
  {
    const int m = mI[w*16 + kq];
    const float* f2row = f2t + ((size_t)(b*NN + m))*64;
    const float* f1row = f1t + ((size_t)(b*NN + n))*64;
    #pragma unroll
    for (int it = 0; it < 4; ++it) {
      int c = it*16 + cg*4;
      float4 v2 = *(const float4*)(f2row + c);
      float4 v1 = *(const float4*)(f1row + c);
      xw[(3 + c + 0)*16 + kq] = v2.x;
      xw[(3 + c + 1)*16 + kq] = v2.y;
      xw[(3 + c + 2)*16 + kq] = v2.z;
      xw[(3 + c + 3)*16 + kq] = v2.w;
      xw[(67 + c + 0)*16 + kq] = v1.x;
      xw[(67 + c + 1)*16 + kq] = v1.y;
      xw[(67 + c + 2)*16 + kq] = v1.z;
      xw[(67 + c + 3)*16 + kq] = v1.w;
    }
    if (lane < 16) {
      float4 p = pos2t[(size_t)b*NN + mI[w*16 + lane]];
      float px = pos1[(b*3 + 0)*NN + n];
      float py = pos1[(b*3 + 1)*NN + n];
      float pz = pos1[(b*3 + 2)*NN + n];
      xw[0*16 + lane] = p.x - px;
      xw[1*16 + lane] = p.y - py;
      xw[2*16 + lane] = p.z - pz;
    }
  }
  __syncthreads();

  const int o4 = lane & 15, pg = lane >> 4;
  float4 a0 = {0,0,0,0}, a1 = {0,0,0,0}, a2 = {0,0,0,0}, a3 = {0,0,0,0};
  const float* wb = wsL + 4*o4;
  const float* xb = xw + 4*pg;
  #pragma unroll 4
  for (int c = 0; c < INCH; ++c) {
    float4 w4 = *(const float4*)(wb + c*64);
    float4 xv = *(const float4*)(xb + c*16);
    FMA4(a0, w4, xv.x); FMA4(a1, w4, xv.y); FMA4(a2, w4, xv.z); FMA4(a3, w4, xv.w);
  }
  {
    size_t basep = ((size_t)(b*NN + n))*KK;
    store4bf(Y0 + (basep + pg*4 + 0)*64 + 4*o4, a0);
    store4bf(Y0 + (basep + pg*4 + 1)*64 + 4*o4, a1);
    store4bf(Y0 + (basep + pg*4 + 2)*64 + 4*o4, a2);
    store4bf(Y0 + (basep + pg*4 + 3)*64 + 4*o4, a3);
  }
  RED4(a0,a1,a2,a3, x, 4*o4 + 0)
  RED4(a0,a1,a2,a3, y, 4*o4 + 1)
  RED4(a0,a1,a2,a3, z, 4*o4 + 2)
  RED4(a0,a1,a2,a3, w, 4*o4 + 3)
  __syncthreads();
  const int slot = blockIdx.x & 31;
  if (t < 64) { atomicAdd(&gS[slot*64 + t], sS[t]); atomicAdd(&gQ[slot*64 + t], sQ[t]); }
}

// ---------- finalize BN stats (sum 32 copies) ----------
__global__ __launch_bounds__(128) void k_finalize(const float* __restrict__ S, const float* __restrict__ Q,
                                                  const float* __restrict__ g, const float* __restrict__ bb_,
                                                  float* __restrict__ A, float* __restrict__ Bt, int ch) {
  int t = threadIdx.x;
  if (t < ch) {
    float s = 0.f, qq = 0.f;
    for (int c = 0; c < 32; ++c) { s += S[c*ch + t]; qq += Q[c*ch + t]; }
    float mean = s * (1.0f / NPOSF);
    float var  = qq * (1.0f / NPOSF) - mean*mean;
    float rs   = 1.0f / sqrtf(var + BNEPS);
    float a    = g[t] * rs;
    A[t] = a; Bt[t] = bb_[t] - mean*a;
  }
}

// ---------- layer 1 ----------
__global__ __launch_bounds__(256) void k_layer1(
    const unsigned short* __restrict__ Y0, const float* __restrict__ A0, const float* __restrict__ B0,
    const float* __restrict__ Wt1, unsigned short* __restrict__ Y1,
    float* __restrict__ gS, float* __restrict__ gQ) {
  extern __shared__ float sm[];
  float* wsL = sm;            // 4096
  float* xs  = sm + 4096;     // 4096
  float* aL  = sm + 8192;     // 64
  float* bL  = aL + 64;       // 64
  float* sS  = bL + 64;       // 64
  float* sQ  = sS + 64;       // 64

  const int t = threadIdx.x;
  const int b = blockIdx.y, n0 = blockIdx.x * 4;
  for (int i = t; i < 1024; i += 256) ((float4*)wsL)[i] = ((const float4*)Wt1)[i];
  if (t < 64)  { aL[t] = A0[t]; bL[t] = B0[t]; }
  if (t < 128) { sS[t] = 0.f; }
  __syncthreads();

  const int w = t >> 6, lane = t & 63, kq = lane >> 2, cg = lane & 3;
  const int n = n0 + w;
  float* xw = xs + w*1024;
  const unsigned short* yrow = Y0 + (((size_t)(b*NN + n))*KK + kq)*64;
  #pragma unroll
  for (int it = 0; it < 4; ++it) {
    int c = it*16 + cg*4;
    ushort4 u = *(const ushort4*)(yrow + c);
    xw[(c + 0)*16 + kq] = fmaxf(bf2f(u.x)*aL[c + 0] + bL[c + 0], 0.f);
    xw[(c + 1)*16 + kq] = fmaxf(bf2f(u.y)*aL[c + 1] + bL[c + 1], 0.f);
    xw[(c + 2)*16 + kq] = fmaxf(bf2f(u.z)*aL[c + 2] + bL[c + 2], 0.f);
    xw[(c + 3)*16 + kq] = fmaxf(bf2f(u.w)*aL[c + 3] + bL[c + 3], 0.f);
  }
  __syncthreads();

  const int o4 = lane & 15, pg = lane >> 4;
  float4 a0 = {0,0,0,0}, a1 = {0,0,0,0}, a2 = {0,0,0,0}, a3 = {0,0,0,0};
  const float* wb = wsL + 4*o4;
  const float* xb = xw + 4*pg;
  #pragma unroll 4
  for (int c = 0; c < 64; ++c) {
    float4 w4 = *(const float4*)(wb + c*64);
    float4 xv = *(const float4*)(xb + c*16);
    FMA4(a0, w4, xv.x); FMA4(a1, w4, xv.y); FMA4(a2, w4, xv.z); FMA4(a3, w4, xv.w);
  }
  {
    size_t basep = ((size_t)(b*NN + n))*KK;
    store4bf(Y1 + (basep + pg*4 + 0)*64 + 4*o4, a0);
    store4bf(Y1 + (basep + pg*4 + 1)*64 + 4*o4, a1);
    store4bf(Y1 + (basep + pg*4 + 2)*64 + 4*o4, a2);
    store4bf(Y1 + (basep + pg*4 + 3)*64 + 4*o4, a3);
  }
  RED4(a0,a1,a2,a3, x, 4*o4 + 0)
  RED4(a0,a1,a2,a3, y, 4*o4 + 1)
  RED4(a0,a1,a2,a3, z, 4*o4 + 2)
  RED4(a0,a1,a2,a3, w, 4*o4 + 3)
  __syncthreads();
  const int slot = blockIdx.x & 31;
  if (t < 64) { atomicAdd(&gS[slot*64 + t], sS[t]); atomicAdd(&gQ[slot*64 + t], sQ[t]); }
}

// ---------- layer 2 stats ----------
__global__ __launch_bounds__(256) void k_l2stats(
    const unsigned short* __restrict__ Y1, const float* __restrict__ A1, const float* __restrict__ B1,
    const float* __restrict__ Wt2, float* __restrict__ gS, float* __restrict__ gQ) {
  extern __shared__ float sm[];
  float* wsL = sm;            // 8192
  float* xs  = sm + 8192;     // 4096
  float* aL  = sm + 12288;    // 64
  float* bL  = aL + 64;       // 64
  float* sS  = bL + 64;       // 128
  float* sQ  = sS + 128;      // 128

  const int t = threadIdx.x;
  const int b = blockIdx.y, n0 = blockIdx.x * 4;
  for (int i = t; i < 2048; i += 256) ((float4*)wsL)[i] = ((const float4*)Wt2)[i];
  if (t < 64) { aL[t] = A1[t]; bL[t] = B1[t]; }
  sS[t] = 0.f;
  __syncthreads();

  const int w = t >> 6, lane = t & 63, kq = lane >> 2, cg = lane & 3;
  const int n = n0 + w;
  float* xw = xs + w*1024;
  const unsigned short* yrow = Y1 + (((size_t)(b*NN + n))*KK + kq)*64;
  #pragma unroll
  for (int it = 0; it < 4; ++it) {
    int c = it*16 + cg*4;
    ushort4 u = *(const ushort4*)(yrow + c);
    xw[(c + 0)*16 + kq] = fmaxf(bf2f(u.x)*aL[c + 0] + bL[c + 0], 0.f);
    xw[(c + 1)*16 + kq] = fmaxf(bf2f(u.y)*aL[c + 1] + bL[c + 1], 0.f);
    xw[(c + 2)*16 + kq] = fmaxf(bf2f(u.z)*aL[c + 2] + bL[c + 2], 0.f);
    xw[(c + 3)*16 + kq] = fmaxf(bf2f(u.w)*aL[c + 3] + bL[c + 3], 0.f);
  }
  __syncthreads();

  const int o4 = lane & 15, pg = lane >> 4;
  float4 c00={0,0,0,0},c01={0,0,0,0},c02={0,0,0,0},c03={0,0,0,0};
  float4 c10={0,0,0,0},c11={0,0,0,0},c12={0,0,0,0},c13={0,0,0,0};
  const float* wbA = wsL + 4*o4;
  const float* wbB = wsL + 64 + 4*o4;
  const float* xb  = xw + 4*pg;
  #pragma unroll 4
  for (int c = 0; c < 64; ++c) {
    float4 xv = *(const float4*)(xb + c*16);
    float4 wA = *(const float4*)(wbA + c*128);
    float4 wB = *(const float4*)(wbB + c*128);
    FMA4(c00, wA, xv.x); FMA4(c01, wA, xv.y); FMA4(c02, wA, xv.z); FMA4(c03, wA, xv.w);
    FMA4(c10, wB, xv.x); FMA4(c11, wB, xv.y); FMA4(c12, wB, xv.z); FMA4(c13, wB, xv.w);
  }
  RED4(c00,c01,c02,c03, x, 4*o4 + 0)
  RED4(c00,c01,c02,c03, y, 4*o4 + 1)
  RED4(c00,c01,c02,c03, z, 4*o4 + 2)
  RED4(c00,c01,c02,c03, w, 4*o4 + 3)
  RED4(c10,c11,c12,c13, x, 64 + 4*o4 + 0)
  RED4(c10,c11,c12,c13, y, 64 + 4*o4 + 1)
  RED4(c10,c11,c12,c13, z, 64 + 4*o4 + 2)
  RED4(c10,c11,c12,c13, w, 64 + 4*o4 + 3)
  __syncthreads();
  const int slot = blockIdx.x & 31;
  if (t < 128) { atomicAdd(&gS[slot*128 + t], sS[t]); atomicAdd(&gQ[slot*128 + t], sQ[t]); }
}

#define MAXC(A0_,A1_,A2_,A3_, comp, chidx) { \
  int ch_ = (chidx); float al_ = aL2[ch_], be_ = bL2[ch_]; \
  float m_ = fmaxf(al_*A0_.comp + be_, 0.f); \
  m_ = fmaxf(m_, fmaxf(al_*A1_.comp + be_, 0.f)); \
  m_ = fmaxf(m_, fmaxf(al_*A2_.comp + be_, 0.f)); \
  m_ = fmaxf(m_, fmaxf(al_*A3_.comp + be_, 0.f)); \
  m_ = fmaxf(m_, __shfl_xor(m_, 16)); m_ = fmaxf(m_, __shfl_xor(m_, 32)); \
  if (pg == 0) oBuf[w*128 + ch_] = m_; \
}

__global__ __launch_bounds__(256) void k_l2final(
    const unsigned short* __restrict__ Y1, const float* __restrict__ A1, const float* __restrict__ B1,
    const float* __restrict__ Wt2, const float* __restrict__ A2, const float* __restrict__ B2,
    float* __restrict__ outF) {
  extern __shared__ float sm[];
  float* wsL  = sm;            // 8192
  float* xs   = sm + 8192;     // 4096
  float* aL   = sm + 12288;    // 64
  float* bL   = aL + 64;       // 64
  float* aL2  = bL + 64;       // 128
  float* bL2  = aL2 + 128;     // 128
  float* oBuf = bL2 + 128;     // 512

  const int t = threadIdx.x;
  const int b = blockIdx.y, n0 = blockIdx.x * 4;
  for (int i = t; i < 2048; i += 256) ((float4*)wsL)[i] = ((const float4*)Wt2)[i];
  if (t < 64)  { aL[t] = A1[t]; bL[t] = B1[t]; }
  if (t < 128) { aL2[t] = A2[t]; bL2[t] = B2[t]; }
  __syncthreads();

  const int w = t >> 6, lane = t & 63, kq = lane >> 2, cg = lane & 3;
  const int n = n0 + w;
  float* xw = xs + w*1024;
  const unsigned short* yrow = Y1 + (((size_t)(b*NN + n))*KK + kq)*64;
  #pragma unroll
  for (int it = 0; it < 4; ++it) {
    int c = it*16 + cg*4;
    ushort4 u = *(const ushort4*)(yrow + c);
    xw[(c + 0)*16 + kq] = fmaxf(bf2f(u.x)*aL[c + 0] + bL[c + 0], 0.f);
    xw[(c + 1)*16 + kq] = fmaxf(bf2f(u.y)*aL[c + 1] + bL[c + 1], 0.f);
    xw[(c + 2)*16 + kq] = fmaxf(bf2f(u.z)*aL[c + 2] + bL[c + 2], 0.f);
    xw[(c + 3)*16 + kq] = fmaxf(bf2f(u.w)*aL[c + 3] + bL[c + 3], 0.f);
  }
  __syncthreads();

  const int o4 = lane & 15, pg = lane >> 4;
  float4 c00={0,0,0,0},c01={0,0,0,0},c02={0,0,0,0},c03={0,0,0,0};
  float4 c10={0,0,0,0},c11={0,0,0,0},c12={0,0,0,0},c13={0,0,0,0};
  const float* wbA = wsL + 4*o4;
  const float* wbB = wsL + 64 + 4*o4;
  const float* xb  = xw + 4*pg;
  #pragma unroll 4
  for (int c = 0; c < 64; ++c) {
    float4 xv = *(const float4*)(xb + c*16);
    float4 wA = *(const float4*)(wbA + c*128);
    float4 wB = *(const float4*)(wbB + c*128);
    FMA4(c00, wA, xv.x); FMA4(c01, wA, xv.y); FMA4(c02, wA, xv.z); FMA4(c03, wA, xv.w);
    FMA4(c10, wB, xv.x); FMA4(c11, wB, xv.y); FMA4(c12, wB, xv.z); FMA4(c13, wB, xv.w);
  }
  MAXC(c00,c01,c02,c03, x, 4*o4 + 0)
  MAXC(c00,c01,c02,c03, y, 4*o4 + 1)
  MAXC(c00,c01,c02,c03, z, 4*o4 + 2)
  MAXC(c00,c01,c02,c03, w, 4*o4 + 3)
  MAXC(c10,c11,c12,c13, x, 64 + 4*o4 + 0)
  MAXC(c10,c11,c12,c13, y, 64 + 4*o4 + 1)
  MAXC(c10,c11,c12,c13, z, 64 + 4*o4 + 2)
  MAXC(c10,c11,c12,c13, w, 64 + 4*o4 + 3)
  __syncthreads();
  #pragma unroll
  for (int e = t; e < 512; e += 256) {
    int ch = e >> 2, nl = e & 3;
    outF[((size_t)b*H2 + ch)*NN + n0 + nl] = oBuf[nl*128 + ch];
  }
}

// ---------- launch ----------
extern "C" void kernel_launch(void* const* d_in, const int* in_sizes, int n_in,
                              void* d_out, int out_size, void* d_ws, size_t ws_size,
                              hipStream_t stream) {
  const float* pos1    = (const float*)d_in[0];
  const float* pos1_re = (const float*)d_in[1];
  const float* pos2    = (const float*)d_in[2];
  const float* f1      = (const float*)d_in[3];
  const float* f2      = (const float*)d_in[4];
  const float* W0 = (const float*)d_in[6];
  const float* g0 = (const float*)d_in[7];
  const float* b0 = (const float*)d_in[8];
  const float* W1 = (const float*)d_in[9];
  const float* g1 = (const float*)d_in[10];
  const float* b1 = (const float*)d_in[11];
  const float* W2 = (const float*)d_in[12];
  const float* g2 = (const float*)d_in[13];
  const float* b2 = (const float*)d_in[14];
  float* out = (float*)d_out;

  // workspace layout (bytes)
  char* ws = (char*)d_ws;
  float* stats = (float*)ws;                 // 16384 floats @0 (65536 B)
  float* S0 = stats;         float* Q0 = stats + 2048;
  float* S1 = stats + 4096;  float* Q1 = stats + 6144;
  float* S2 = stats + 8192;  float* Q2 = stats + 12288;
  float* prm = (float*)(ws + 65536);         // 512 floats
  float* A0 = prm;       float* B0a = prm + 64;
  float* A1 = prm + 128; float* B1a = prm + 192;
  float* A2 = prm + 256; float* B2a = prm + 384;
  float* Wt0 = (float*)(ws + 67584);         // 8384 f
  float* Wt1 = (float*)(ws + 101120);        // 4096 f
  float* Wt2 = (float*)(ws + 117504);        // 8192 f -> ends 150272
  unsigned short* idxb = (unsigned short*)(ws + 150528);   // 1,048,576 B
  float4* pos2t = (float4*)(ws + 1199104);   // 524,288 B
  float*  f2t   = (float*)(ws + 1723392);    // 8 MB
  float*  f1t   = (float*)(ws + 10112000);   // 8 MB
  unsigned short* Y0 = (unsigned short*)(ws + 18500608);   // 64 MB
  unsigned short* Y1 = (unsigned short*)(ws + 85609472);   // 64 MB -> ends 152,718,336
  if (ws_size < 152718336u) return;

  k_zero<<<dim3(64), 256, 0, stream>>>(stats);
  k_wt<<<dim3(81), 256, 0, stream>>>(W0, W1, W2, Wt0, Wt1, Wt2);
  hipMemcpyAsync(out, pos1, (size_t)BB*3*NN*sizeof(float), hipMemcpyDeviceToDevice, stream);

  k_pos2t<<<dim3(BB*NN/256), 256, 0, stream>>>(pos2, pos2t);
  k_transpose<<<dim3(NN/32, CC/32, BB), dim3(32, 8), 0, stream>>>(f2, f2t);
  k_transpose<<<dim3(NN/32, CC/32, BB), dim3(32, 8), 0, stream>>>(f1, f1t);
  k_knn<<<dim3(NN/8, BB), 512, 0, stream>>>(pos1_re, pos2t, idxb);

  k_layer0<<<dim3(NN/2, BB), 128, 12736*4, stream>>>(idxb, pos2t, pos1, f2t, f1t, Wt0, Y0, S0, Q0);
  k_finalize<<<1, 128, 0, stream>>>(S0, Q0, g0, b0, A0, B0a, 64);

  k_layer1<<<dim3(NN/4, BB), 256, 8448*4, stream>>>(Y0, A0, B0a, Wt1, Y1, S1, Q1);
  k_finalize<<<1, 128, 0, stream>>>(S1, Q1, g1, b1, A1, B1a, 64);

  k_l2stats<<<dim3(NN/4, BB), 256, 12672*4, stream>>>(Y1, A1, B1a, Wt2, S2, Q2);
  k_finalize<<<1, 128, 0, stream>>>(S2, Q2, g2, b2, A2, B2a, 128);

  k_l2final<<<dim3(NN/4, BB), 256, 13184*4, stream>>>(Y1, A1, B1a, Wt2, A2, B2a, out + (size_t)BB*3*NN);
}

// Round 7
// 688.945 us; speedup vs baseline: 2.3452x; 1.2169x over previous
//
#include <hip/hip_runtime.h>
#include <hip/hip_bf16.h>
#include <cstdint>
#include <cstddef>

#define BB   8
#define NN   4096
#define CC   64
#define KK   16
#define H2   128
#define NPOSF 524288.0f
#define BNEPS 1e-5f
#define FBIG 3.4e38f

typedef __attribute__((ext_vector_type(8))) short  short8;
typedef __attribute__((ext_vector_type(4))) float  f32x4;

#define MFMA(a,b,c) __builtin_amdgcn_mfma_f32_16x16x32_bf16(a, b, c, 0, 0, 0)

// ---------- helpers ----------
__device__ __forceinline__ unsigned short f2bf(float x) {
  union { float f; unsigned u; } v; v.f = x;
  unsigned u = v.u;
  return (unsigned short)((u + 0x7fffu + ((u >> 16) & 1u)) >> 16);
}
__device__ __forceinline__ float bf2f(unsigned short h) {
  union { unsigned u; float f; } v; v.u = ((unsigned)h) << 16; return v.f;
}

// ---------- utility kernels ----------
__global__ __launch_bounds__(256) void k_zero(float* p) {
  p[blockIdx.x * 256 + threadIdx.x] = 0.f;   // 16384 floats of stats
}

// pos2t[b][n] = (x,y,z, x^2+y^2+z^2) — PINNED to np rounding
__global__ __launch_bounds__(256) void k_pos2t(const float* __restrict__ pos2, float4* __restrict__ out) {
  int i = blockIdx.x * 256 + threadIdx.x;
  int b = i >> 12, n = i & 4095;
  float x = pos2[(b*3 + 0)*NN + n];
  float y = pos2[(b*3 + 1)*NN + n];
  float z = pos2[(b*3 + 2)*NN + n];
  float w = __fadd_rn(__fadd_rn(__fmul_rn(x,x), __fmul_rn(y,y)), __fmul_rn(z,z));
  out[i] = make_float4(x, y, z, w);
}

// [B,64,N] fp32 -> [B,N,64] bf16
__global__ __launch_bounds__(256) void k_transposeb(const float* __restrict__ in, unsigned short* __restrict__ out) {
  __shared__ float tile[32][33];
  int b = blockIdx.z;
  int n0 = blockIdx.x * 32, c0 = blockIdx.y * 32;
  int tx = threadIdx.x, ty = threadIdx.y;
  #pragma unroll
  for (int i = 0; i < 32; i += 8)
    tile[ty + i][tx] = in[((size_t)(b*CC + c0 + ty + i))*NN + n0 + tx];
  __syncthreads();
  #pragma unroll
  for (int i = 0; i < 32; i += 8)
    out[((size_t)(b*NN + n0 + ty + i))*CC + c0 + tx] = f2bf(tile[tx][ty + i]);
}

// ---------- weight pre-pack: A-fragment order, split bf16 hi/lo ----------
// A[m=lane&15][k=quad*8+j] per mfma_f32_16x16x32_bf16. Layer0 input channel
// reorder: c'<128 -> orig c'+3 (f2 then f1), c'=128..130 -> pos_diff, pad->0.
__global__ __launch_bounds__(256) void k_wt(const float* __restrict__ W0, const float* __restrict__ W1,
                                            const float* __restrict__ W2, unsigned short* __restrict__ Apk0,
                                            unsigned short* __restrict__ Apk1, unsigned short* __restrict__ Apk2) {
  int i = blockIdx.x * 256 + threadIdx.x;
  if (i < 1280) {            // L0: 4 mt x 5 s x 64 lanes
    int mt = i / 320, r = i % 320, s = r / 64, lane = r % 64;
    int o = mt*16 + (lane & 15), q = lane >> 4, fi = mt*5 + s;
    #pragma unroll
    for (int j = 0; j < 8; ++j) {
      int c = s*32 + q*8 + j;
      float w = 0.f;
      if (c < 131) { int cs = (c < 128) ? (c + 3) : (c - 128); w = W0[o*131 + cs]; }
      unsigned short hi = f2bf(w);
      unsigned short lo = f2bf(w - bf2f(hi));
      Apk0[((size_t)(fi)*64 + lane)*8 + j]        = hi;
      Apk0[((size_t)(20 + fi)*64 + lane)*8 + j]   = lo;
    }
  } else if (i < 1792) {     // L1: 4 mt x 2 s
    int k = i - 1280, mt = k / 128, r = k % 128, s = r / 64, lane = r % 64;
    int o = mt*16 + (lane & 15), q = lane >> 4, fi = mt*2 + s;
    #pragma unroll
    for (int j = 0; j < 8; ++j) {
      int c = s*32 + q*8 + j;
      float w = W1[o*64 + c];
      unsigned short hi = f2bf(w);
      unsigned short lo = f2bf(w - bf2f(hi));
      Apk1[((size_t)(fi)*64 + lane)*8 + j]        = hi;
      Apk1[((size_t)(8 + fi)*64 + lane)*8 + j]    = lo;
    }
  } else if (i < 2816) {     // L2: 8 mt x 2 s
    int k = i - 1792, mt = k / 128, r = k % 128, s = r / 64, lane = r % 64;
    int o = mt*16 + (lane & 15), q = lane >> 4, fi = mt*2 + s;
    #pragma unroll
    for (int j = 0; j < 8; ++j) {
      int c = s*32 + q*8 + j;
      float w = W2[o*64 + c];
      unsigned short hi = f2bf(w);
      unsigned short lo = f2bf(w - bf2f(hi));
      Apk2[((size_t)(fi)*64 + lane)*8 + j]        = hi;
      Apk2[((size_t)(16 + fi)*64 + lane)*8 + j]   = lo;
    }
  }
}

// ---------- KNN (R6-validated, DO NOT TOUCH: set-exact vs np top_k) ----------
__global__ __launch_bounds__(512) void k_knn(const float* __restrict__ pos1_re,
                                             const float4* __restrict__ pos2t,
                                             unsigned short* __restrict__ idxOut) {
  const int lane = threadIdx.x & 63;
  const int wv   = threadIdx.x >> 6;
  const int b = blockIdx.y;
  const int n = blockIdx.x * 8 + wv;

  const float qx = pos1_re[(b*3 + 0)*NN + n];
  const float qy = pos1_re[(b*3 + 1)*NN + n];
  const float qz = pos1_re[(b*3 + 2)*NN + n];
  const float q2 = __fadd_rn(__fadd_rn(__fmul_rn(qx,qx), __fmul_rn(qy,qy)), __fmul_rn(qz,qz));

  unsigned bd  = 0xFFFFFFFFu;
  unsigned bix = 0u;
  unsigned tau = 0xFFFFFFFFu;

  const float4* rp = pos2t + (size_t)b*NN;
  for (int it = 0; it < 64; ++it) {
    float4 r = rp[it*64 + lane];
    float dot = __fadd_rn(__fadd_rn(__fmul_rn(qx,r.x), __fmul_rn(qy,r.y)), __fmul_rn(qz,r.z));
    float d   = __fsub_rn(__fadd_rn(q2, r.w), __fmul_rn(2.0f, dot));
    unsigned du = __float_as_uint(d);
    du ^= (du >> 31) ? 0xFFFFFFFFu : 0x80000000u;

    unsigned long long mask = __ballot(du < tau);
    while (mask) {
      const int l = __ffsll((unsigned long long)mask) - 1;
      mask &= (mask - 1);
      const unsigned sd = (unsigned)__builtin_amdgcn_readlane((int)du, l);
      if (sd >= tau) continue;
      const unsigned sidx = (unsigned)(it*64 + l);
      int m = (bd > sd) ? 1 : 0;
      int pm = __builtin_amdgcn_update_dpp(0, m, 0x111, 0xF, 0xF, true);
      unsigned sb = (unsigned)__builtin_amdgcn_update_dpp(0, (int)bd,  0x111, 0xF, 0xF, true);
      unsigned si = (unsigned)__builtin_amdgcn_update_dpp(0, (int)bix, 0x111, 0xF, 0xF, true);
      if (m) { bd = pm ? sb : sd; bix = pm ? si : sidx; }
      tau = (unsigned)__builtin_amdgcn_readlane((int)bd, 15);
    }
  }

  if (lane < 16) {
    idxOut[((size_t)(b*NN + n))*KK + lane] = (unsigned short)bix;
  }
}

// ---------- epilogue stat macro: reduce over col lanes (kpos), add to LDS ----------
#define STAT4(ACC, CH0) { \
  _Pragma("unroll") \
  for (int rg = 0; rg < 4; ++rg) { \
    float v = (ACC)[rg]; float s_ = v, qq_ = v*v; \
    s_ += __shfl_xor(s_, 1); s_ += __shfl_xor(s_, 2); s_ += __shfl_xor(s_, 4); s_ += __shfl_xor(s_, 8); \
    qq_ += __shfl_xor(qq_, 1); qq_ += __shfl_xor(qq_, 2); qq_ += __shfl_xor(qq_, 4); qq_ += __shfl_xor(qq_, 8); \
    if (cl == 0) { atomicAdd(&sS[(CH0) + rg], s_); atomicAdd(&sQ[(CH0) + rg], qq_); } \
  } }

// ---------- layer 0: gather -> MFMA(64out x 160K) -> Y0 + stats ----------
__global__ __launch_bounds__(256) void k_layer0(
    const unsigned short* __restrict__ nidx, const float4* __restrict__ pos2t,
    const float* __restrict__ pos1, const unsigned short* __restrict__ f2b,
    const unsigned short* __restrict__ f1b, const unsigned short* __restrict__ Apk0,
    unsigned short* __restrict__ Y0, float* __restrict__ gS, float* __restrict__ gQ) {
  __shared__ __align__(16) unsigned short Wf[2*20*64*8];   // 40 KB
  __shared__ __align__(16) unsigned short Xs[4*16*160];    // 20 KB (pitch 160 bf16 = 320B)
  __shared__ float sS[64], sQ[64];

  const int t = threadIdx.x, lane = t & 63, wv = t >> 6;
  const int b = blockIdx.y, n = blockIdx.x*4 + wv;
  const int cl = lane & 15, q = lane >> 4;

  for (int i = t; i < 2560; i += 256) ((short8*)Wf)[i] = ((const short8*)Apk0)[i];
  if (t < 64) { sS[t] = 0.f; sQ[t] = 0.f; }

  unsigned short* Xw = Xs + wv*16*160;
  int mreg = 0;
  if (lane < 16) mreg = (int)nidx[((size_t)(b*NN + n))*KK + lane];
  if (lane < 16) {
    float4 pp = pos2t[(size_t)b*NN + mreg];
    float px = pos1[(b*3 + 0)*NN + n];
    float py = pos1[(b*3 + 1)*NN + n];
    float pz = pos1[(b*3 + 2)*NN + n];
    ushort4 pd; pd.x = f2bf(pp.x - px); pd.y = f2bf(pp.y - py); pd.z = f2bf(pp.z - pz); pd.w = 0;
    *(ushort4*)(Xw + lane*160 + 128) = pd;
    ushort4 z4 = {0,0,0,0};
    *(ushort4*)(Xw + lane*160 + 132) = z4;
    short8 z8 = {0,0,0,0,0,0,0,0};
    *(short8*)(Xw + lane*160 + 136) = z8;
    *(short8*)(Xw + lane*160 + 144) = z8;
    *(short8*)(Xw + lane*160 + 152) = z8;
  }
  #pragma unroll
  for (int p = 0; p < 2; ++p) {
    int kp = (lane >> 3) + p*8, chunk = lane & 7;
    int m = __shfl(mreg, kp);
    short8 v2 = *(const short8*)(f2b + ((size_t)(b*NN + m))*64 + chunk*8);
    *(short8*)(Xw + kp*160 + chunk*8) = v2;
    short8 v1 = *(const short8*)(f1b + ((size_t)(b*NN + n))*64 + chunk*8);
    *(short8*)(Xw + kp*160 + 64 + chunk*8) = v1;
  }
  __syncthreads();

  f32x4 acc[4] = {{0,0,0,0},{0,0,0,0},{0,0,0,0},{0,0,0,0}};
  #pragma unroll
  for (int s = 0; s < 5; ++s) {
    short8 bf = *(const short8*)(Xw + cl*160 + s*32 + q*8);
    #pragma unroll
    for (int mt = 0; mt < 4; ++mt) {
      short8 ah = *(const short8*)(Wf + ((mt*5 + s)*64 + lane)*8);
      short8 al = *(const short8*)(Wf + ((20 + mt*5 + s)*64 + lane)*8);
      acc[mt] = MFMA(ah, bf, acc[mt]);
      acc[mt] = MFMA(al, bf, acc[mt]);
    }
  }

  #pragma unroll
  for (int mt = 0; mt < 4; ++mt) {
    STAT4(acc[mt], mt*16 + q*4)
    ushort4 pk; pk.x = f2bf(acc[mt][0]); pk.y = f2bf(acc[mt][1]);
    pk.z = f2bf(acc[mt][2]); pk.w = f2bf(acc[mt][3]);
    *(ushort4*)(Xw + cl*160 + mt*16 + q*4) = pk;
  }
  #pragma unroll
  for (int p = 0; p < 2; ++p) {
    int kp = (lane >> 3) + p*8, chunk = lane & 7;
    short8 v = *(const short8*)(Xw + kp*160 + chunk*8);
    *(short8*)(Y0 + (((size_t)(b*NN + n))*KK + kp)*64 + chunk*8) = v;
  }
  __syncthreads();
  const int slot = blockIdx.x & 31;
  if (t < 64) { atomicAdd(&gS[slot*64 + t], sS[t]); atomicAdd(&gQ[slot*64 + t], sQ[t]); }
}

// ---------- finalize BN stats (sum 32 copies) ----------
__global__ __launch_bounds__(128) void k_finalize(const float* __restrict__ S, const float* __restrict__ Q,
                                                  const float* __restrict__ g, const float* __restrict__ bb_,
                                                  float* __restrict__ A, float* __restrict__ Bt, int ch) {
  int t = threadIdx.x;
  if (t < ch) {
    float s = 0.f, qq = 0.f;
    for (int c = 0; c < 32; ++c) { s += S[c*ch + t]; qq += Q[c*ch + t]; }
    float mean = s * (1.0f / NPOSF);
    float var  = qq * (1.0f / NPOSF) - mean*mean;
    float rs   = 1.0f / sqrtf(var + BNEPS);
    float a    = g[t] * rs;
    A[t] = a; Bt[t] = bb_[t] - mean*a;
  }
}

// ---------- layer 1: bn0+relu(Y0) -> MFMA(64x64) -> Y1 + stats ----------
__global__ __launch_bounds__(256) void k_layer1(
    const unsigned short* __restrict__ Y0, const float* __restrict__ A0, const float* __restrict__ B0,
    const unsigned short* __restrict__ Apk1, unsigned short* __restrict__ Y1,
    float* __restrict__ gS, float* __restrict__ gQ) {
  __shared__ __align__(16) unsigned short Wf[2*8*64*8];    // 16 KB
  __shared__ __align__(16) unsigned short Xs[4*16*80];     // 10 KB (pitch 80 bf16 = 160B)
  __shared__ float aLs[64], bLs[64], sS[64], sQ[64];

  const int t = threadIdx.x, lane = t & 63, wv = t >> 6;
  const int b = blockIdx.y, n = blockIdx.x*4 + wv;
  const int cl = lane & 15, q = lane >> 4;

  for (int i = t; i < 1024; i += 256) ((short8*)Wf)[i] = ((const short8*)Apk1)[i];
  if (t < 64) { aLs[t] = A0[t]; bLs[t] = B0[t]; sS[t] = 0.f; sQ[t] = 0.f; }
  __syncthreads();

  unsigned short* Xw = Xs + wv*16*80;
  const unsigned short* yrow = Y0 + ((size_t)(b*NN + n))*KK*64;
  #pragma unroll
  for (int p = 0; p < 2; ++p) {
    int kp = (lane >> 3) + p*8, chunk = lane & 7;
    short8 u = *(const short8*)(yrow + kp*64 + chunk*8);
    short8 xv;
    #pragma unroll
    for (int j = 0; j < 8; ++j) {
      int c = chunk*8 + j;
      float x = fmaxf(bf2f((unsigned short)u[j])*aLs[c] + bLs[c], 0.f);
      xv[j] = (short)f2bf(x);
    }
    *(short8*)(Xw + kp*80 + chunk*8) = xv;
  }

  f32x4 acc[4] = {{0,0,0,0},{0,0,0,0},{0,0,0,0},{0,0,0,0}};
  #pragma unroll
  for (int s = 0; s < 2; ++s) {
    short8 bf = *(const short8*)(Xw + cl*80 + s*32 + q*8);
    #pragma unroll
    for (int mt = 0; mt < 4; ++mt) {
      short8 ah = *(const short8*)(Wf + ((mt*2 + s)*64 + lane)*8);
      short8 al = *(const short8*)(Wf + ((8 + mt*2 + s)*64 + lane)*8);
      acc[mt] = MFMA(ah, bf, acc[mt]);
      acc[mt] = MFMA(al, bf, acc[mt]);
    }
  }

  #pragma unroll
  for (int mt = 0; mt < 4; ++mt) {
    STAT4(acc[mt], mt*16 + q*4)
    ushort4 pk; pk.x = f2bf(acc[mt][0]); pk.y = f2bf(acc[mt][1]);
    pk.z = f2bf(acc[mt][2]); pk.w = f2bf(acc[mt][3]);
    *(ushort4*)(Xw + cl*80 + mt*16 + q*4) = pk;
  }
  #pragma unroll
  for (int p = 0; p < 2; ++p) {
    int kp = (lane >> 3) + p*8, chunk = lane & 7;
    short8 v = *(const short8*)(Xw + kp*80 + chunk*8);
    *(short8*)(Y1 + (((size_t)(b*NN + n))*KK + kp)*64 + chunk*8) = v;
  }
  __syncthreads();
  const int slot = blockIdx.x & 31;
  if (t < 64) { atomicAdd(&gS[slot*64 + t], sS[t]); atomicAdd(&gQ[slot*64 + t], sQ[t]); }
}

// ---------- layer 2 stats: bn1+relu(Y1) -> MFMA(128x64) -> stats only ----------
__global__ __launch_bounds__(256) void k_l2stats(
    const unsigned short* __restrict__ Y1, const float* __restrict__ A1, const float* __restrict__ B1,
    const unsigned short* __restrict__ Apk2, float* __restrict__ gS, float* __restrict__ gQ) {
  __shared__ __align__(16) unsigned short Wf[2*16*64*8];   // 32 KB
  __shared__ __align__(16) unsigned short Xs[4*16*80];     // 10 KB
  __shared__ float aLs[64], bLs[64];
  __shared__ float sS[128], sQ[128];

  const int t = threadIdx.x, lane = t & 63, wv = t >> 6;
  const int b = blockIdx.y, n = blockIdx.x*4 + wv;
  const int cl = lane & 15, q = lane >> 4;

  for (int i = t; i < 2048; i += 256) ((short8*)Wf)[i] = ((const short8*)Apk2)[i];
  if (t < 64) { aLs[t] = A1[t]; bLs[t] = B1[t]; }
  if (t < 128) { sS[t] = 0.f; sQ[t] = 0.f; }
  __syncthreads();

  unsigned short* Xw = Xs + wv*16*80;
  const unsigned short* yrow = Y1 + ((size_t)(b*NN + n))*KK*64;
  #pragma unroll
  for (int p = 0; p < 2; ++p) {
    int kp = (lane >> 3) + p*8, chunk = lane & 7;
    short8 u = *(const short8*)(yrow + kp*64 + chunk*8);
    short8 xv;
    #pragma unroll
    for (int j = 0; j < 8; ++j) {
      int c = chunk*8 + j;
      float x = fmaxf(bf2f((unsigned short)u[j])*aLs[c] + bLs[c], 0.f);
      xv[j] = (short)f2bf(x);
    }
    *(short8*)(Xw + kp*80 + chunk*8) = xv;
  }

  f32x4 acc[8] = {{0,0,0,0},{0,0,0,0},{0,0,0,0},{0,0,0,0},{0,0,0,0},{0,0,0,0},{0,0,0,0},{0,0,0,0}};
  #pragma unroll
  for (int s = 0; s < 2; ++s) {
    short8 bf = *(const short8*)(Xw + cl*80 + s*32 + q*8);
    #pragma unroll
    for (int mt = 0; mt < 8; ++mt) {
      short8 ah = *(const short8*)(Wf + ((mt*2 + s)*64 + lane)*8);
      short8 al = *(const short8*)(Wf + ((16 + mt*2 + s)*64 + lane)*8);
      acc[mt] = MFMA(ah, bf, acc[mt]);
      acc[mt] = MFMA(al, bf, acc[mt]);
    }
  }

  #pragma unroll
  for (int mt = 0; mt < 8; ++mt) {
    STAT4(acc[mt], mt*16 + q*4)
  }
  __syncthreads();
  const int slot = blockIdx.x & 31;
  if (t < 128) { atomicAdd(&gS[slot*128 + t], sS[t]); atomicAdd(&gQ[slot*128 + t], sQ[t]); }
}

// ---------- layer 2 final: recompute y2, bn2+relu+max over k -> out ----------
__global__ __launch_bounds__(256) void k_l2final(
    const unsigned short* __restrict__ Y1, const float* __restrict__ A1, const float* __restrict__ B1,
    const unsigned short* __restrict__ Apk2, const float* __restrict__ A2, const float* __restrict__ B2,
    float* __restrict__ outF) {
  __shared__ __align__(16) unsigned short Wf[2*16*64*8];   // 32 KB
  __shared__ __align__(16) unsigned short Xs[4*16*80];     // 10 KB
  __shared__ float aLs[64], bLs[64];
  __shared__ float a2s[128], b2s[128];
  __shared__ float oBuf[4*128];

  const int t = threadIdx.x, lane = t & 63, wv = t >> 6;
  const int b = blockIdx.y, n = blockIdx.x*4 + wv, n0 = blockIdx.x*4;
  const int cl = lane & 15, q = lane >> 4;

  for (int i = t; i < 2048; i += 256) ((short8*)Wf)[i] = ((const short8*)Apk2)[i];
  if (t < 64) { aLs[t] = A1[t]; bLs[t] = B1[t]; }
  if (t < 128) { a2s[t] = A2[t]; b2s[t] = B2[t]; }
  __syncthreads();

  unsigned short* Xw = Xs + wv*16*80;
  const unsigned short* yrow = Y1 + ((size_t)(b*NN + n))*KK*64;
  #pragma unroll
  for (int p = 0; p < 2; ++p) {
    int kp = (lane >> 3) + p*8, chunk = lane & 7;
    short8 u = *(const short8*)(yrow + kp*64 + chunk*8);
    short8 xv;
    #pragma unroll
    for (int j = 0; j < 8; ++j) {
      int c = chunk*8 + j;
      float x = fmaxf(bf2f((unsigned short)u[j])*aLs[c] + bLs[c], 0.f);
      xv[j] = (short)f2bf(x);
    }
    *(short8*)(Xw + kp*80 + chunk*8) = xv;
  }

  f32x4 acc[8] = {{0,0,0,0},{0,0,0,0},{0,0,0,0},{0,0,0,0},{0,0,0,0},{0,0,0,0},{0,0,0,0},{0,0,0,0}};
  #pragma unroll
  for (int s = 0; s < 2; ++s) {
    short8 bf = *(const short8*)(Xw + cl*80 + s*32 + q*8);
    #pragma unroll
    for (int mt = 0; mt < 8; ++mt) {
      short8 ah = *(const short8*)(Wf + ((mt*2 + s)*64 + lane)*8);
      short8 al = *(const short8*)(Wf + ((16 + mt*2 + s)*64 + lane)*8);
      acc[mt] = MFMA(ah, bf, acc[mt]);
      acc[mt] = MFMA(al, bf, acc[mt]);
    }
  }

  #pragma unroll
  for (int mt = 0; mt < 8; ++mt) {
    float mx[4];
    #pragma unroll
    for (int rg = 0; rg < 4; ++rg) {
      int ch = mt*16 + q*4 + rg;
      float v = fmaxf(acc[mt][rg]*a2s[ch] + b2s[ch], 0.f);
      v = fmaxf(v, __shfl_xor(v, 1));
      v = fmaxf(v, __shfl_xor(v, 2));
      v = fmaxf(v, __shfl_xor(v, 4));
      v = fmaxf(v, __shfl_xor(v, 8));
      mx[rg] = v;
    }
    if (cl == 0) {
      *(float4*)(oBuf + wv*128 + mt*16 + q*4) = make_float4(mx[0], mx[1], mx[2], mx[3]);
    }
  }
  __syncthreads();
  if (t < 128) {
    float4 o = make_float4(oBuf[t], oBuf[128 + t], oBuf[256 + t], oBuf[384 + t]);
    *(float4*)(outF + ((size_t)(b*H2 + t))*NN + n0) = o;
  }
}

// ---------- launch ----------
extern "C" void kernel_launch(void* const* d_in, const int* in_sizes, int n_in,
                              void* d_out, int out_size, void* d_ws, size_t ws_size,
                              hipStream_t stream) {
  const float* pos1    = (const float*)d_in[0];
  const float* pos1_re = (const float*)d_in[1];
  const float* pos2    = (const float*)d_in[2];
  const float* f1      = (const float*)d_in[3];
  const float* f2      = (const float*)d_in[4];
  const float* W0 = (const float*)d_in[6];
  const float* g0 = (const float*)d_in[7];
  const float* b0 = (const float*)d_in[8];
  const float* W1 = (const float*)d_in[9];
  const float* g1 = (const float*)d_in[10];
  const float* b1 = (const float*)d_in[11];
  const float* W2 = (const float*)d_in[12];
  const float* g2 = (const float*)d_in[13];
  const float* b2 = (const float*)d_in[14];
  float* out = (float*)d_out;

  // workspace layout (bytes)
  char* ws = (char*)d_ws;
  float* stats = (float*)ws;                 // 65536 B
  float* S0 = stats;         float* Q0 = stats + 2048;
  float* S1 = stats + 4096;  float* Q1 = stats + 6144;
  float* S2 = stats + 8192;  float* Q2 = stats + 12288;
  float* prm = (float*)(ws + 65536);         // 2048 B
  float* A0 = prm;       float* B0a = prm + 64;
  float* A1 = prm + 128; float* B1a = prm + 192;
  float* A2 = prm + 256; float* B2a = prm + 384;
  unsigned short* Apk0 = (unsigned short*)(ws + 67584);    // 40960 B
  unsigned short* Apk1 = (unsigned short*)(ws + 108544);   // 16384 B
  unsigned short* Apk2 = (unsigned short*)(ws + 124928);   // 32768 B -> 157696
  unsigned short* idxb = (unsigned short*)(ws + 157696);   // 1 MB -> 1206272
  float4* pos2t        = (float4*)(ws + 1206272);          // 512 KB -> 1730560
  unsigned short* f2b  = (unsigned short*)(ws + 1730560);  // 4 MB -> 5924864
  unsigned short* f1b  = (unsigned short*)(ws + 5924864);  // 4 MB -> 10119168
  unsigned short* Y0   = (unsigned short*)(ws + 10119168); // 64 MB -> 77228032
  unsigned short* Y1   = (unsigned short*)(ws + 77228032); // 64 MB -> 144336896
  if (ws_size < 144336896u) return;

  k_zero<<<dim3(64), 256, 0, stream>>>(stats);
  k_wt<<<dim3(11), 256, 0, stream>>>(W0, W1, W2, Apk0, Apk1, Apk2);
  hipMemcpyAsync(out, pos1, (size_t)BB*3*NN*sizeof(float), hipMemcpyDeviceToDevice, stream);

  k_pos2t<<<dim3(BB*NN/256), 256, 0, stream>>>(pos2, pos2t);
  k_transposeb<<<dim3(NN/32, CC/32, BB), dim3(32, 8), 0, stream>>>(f2, f2b);
  k_transposeb<<<dim3(NN/32, CC/32, BB), dim3(32, 8), 0, stream>>>(f1, f1b);
  k_knn<<<dim3(NN/8, BB), 512, 0, stream>>>(pos1_re, pos2t, idxb);

  k_layer0<<<dim3(NN/4, BB), 256, 0, stream>>>(idxb, pos2t, pos1, f2b, f1b, Apk0, Y0, S0, Q0);
  k_finalize<<<1, 128, 0, stream>>>(S0, Q0, g0, b0, A0, B0a, 64);

  k_layer1<<<dim3(NN/4, BB), 256, 0, stream>>>(Y0, A0, B0a, Apk1, Y1, S1, Q1);
  k_finalize<<<1, 128, 0, stream>>>(S1, Q1, g1, b1, A1, B1a, 64);

  k_l2stats<<<dim3(NN/4, BB), 256, 0, stream>>>(Y1, A1, B1a, Apk2, S2, Q2);
  k_finalize<<<1, 128, 0, stream>>>(S2, Q2, g2, b2, A2, B2a, 128);

  k_l2final<<<dim3(NN/4, BB), 256, 0, stream>>>(Y1, A1, B1a, Apk2, A2, B2a, out + (size_t)BB*3*NN);
}

// Round 8
// 605.142 us; speedup vs baseline: 2.6699x; 1.1385x over previous
//
#include <hip/hip_runtime.h>
#include <hip/hip_bf16.h>
#include <cstdint>
#include <cstddef>

#define BB   8
#define NN   4096
#define CC   64
#define KK   16
#define H2   128
#define NPOSF 524288.0f
#define BNEPS 1e-5f

typedef __attribute__((ext_vector_type(8))) short  short8;
typedef __attribute__((ext_vector_type(4))) float  f32x4;

#define MFMA(a,b,c) __builtin_amdgcn_mfma_f32_16x16x32_bf16(a, b, c, 0, 0, 0)

// ---------- helpers ----------
__device__ __forceinline__ unsigned short f2bf(float x) {
  union { float f; unsigned u; } v; v.f = x;
  unsigned u = v.u;
  return (unsigned short)((u + 0x7fffu + ((u >> 16) & 1u)) >> 16);
}
__device__ __forceinline__ float bf2f(unsigned short h) {
  union { unsigned u; float f; } v; v.u = ((unsigned)h) << 16; return v.f;
}

// ---------- utility kernels ----------
__global__ __launch_bounds__(256) void k_zero(float* p) {
  p[blockIdx.x * 256 + threadIdx.x] = 0.f;   // 16384 floats of stats
}

// pos2t[b][n] = (x,y,z, x^2+y^2+z^2) — PINNED to np rounding
__global__ __launch_bounds__(256) void k_pos2t(const float* __restrict__ pos2, float4* __restrict__ out) {
  int i = blockIdx.x * 256 + threadIdx.x;
  int b = i >> 12, n = i & 4095;
  float x = pos2[(b*3 + 0)*NN + n];
  float y = pos2[(b*3 + 1)*NN + n];
  float z = pos2[(b*3 + 2)*NN + n];
  float w = __fadd_rn(__fadd_rn(__fmul_rn(x,x), __fmul_rn(y,y)), __fmul_rn(z,z));
  out[i] = make_float4(x, y, z, w);
}

// [B,64,N] fp32 -> [B,N,64] bf16
__global__ __launch_bounds__(256) void k_transposeb(const float* __restrict__ in, unsigned short* __restrict__ out) {
  __shared__ float tile[32][33];
  int b = blockIdx.z;
  int n0 = blockIdx.x * 32, c0 = blockIdx.y * 32;
  int tx = threadIdx.x, ty = threadIdx.y;
  #pragma unroll
  for (int i = 0; i < 32; i += 8)
    tile[ty + i][tx] = in[((size_t)(b*CC + c0 + ty + i))*NN + n0 + tx];
  __syncthreads();
  #pragma unroll
  for (int i = 0; i < 32; i += 8)
    out[((size_t)(b*NN + n0 + ty + i))*CC + c0 + tx] = f2bf(tile[tx][ty + i]);
}

// ---------- weight pre-pack: A-fragment order, split bf16 hi/lo ----------
__global__ __launch_bounds__(256) void k_wt(const float* __restrict__ W0, const float* __restrict__ W1,
                                            const float* __restrict__ W2, unsigned short* __restrict__ Apk0,
                                            unsigned short* __restrict__ Apk1, unsigned short* __restrict__ Apk2) {
  int i = blockIdx.x * 256 + threadIdx.x;
  if (i < 1280) {            // L0: 4 mt x 5 s x 64 lanes
    int mt = i / 320, r = i % 320, s = r / 64, lane = r % 64;
    int o = mt*16 + (lane & 15), q = lane >> 4, fi = mt*5 + s;
    #pragma unroll
    for (int j = 0; j < 8; ++j) {
      int c = s*32 + q*8 + j;
      float w = 0.f;
      if (c < 131) { int cs = (c < 128) ? (c + 3) : (c - 128); w = W0[o*131 + cs]; }
      unsigned short hi = f2bf(w);
      unsigned short lo = f2bf(w - bf2f(hi));
      Apk0[((size_t)(fi)*64 + lane)*8 + j]        = hi;
      Apk0[((size_t)(20 + fi)*64 + lane)*8 + j]   = lo;
    }
  } else if (i < 1792) {     // L1: 4 mt x 2 s
    int k = i - 1280, mt = k / 128, r = k % 128, s = r / 64, lane = r % 64;
    int o = mt*16 + (lane & 15), q = lane >> 4, fi = mt*2 + s;
    #pragma unroll
    for (int j = 0; j < 8; ++j) {
      int c = s*32 + q*8 + j;
      float w = W1[o*64 + c];
      unsigned short hi = f2bf(w);
      unsigned short lo = f2bf(w - bf2f(hi));
      Apk1[((size_t)(fi)*64 + lane)*8 + j]        = hi;
      Apk1[((size_t)(8 + fi)*64 + lane)*8 + j]    = lo;
    }
  } else if (i < 2816) {     // L2: 8 mt x 2 s
    int k = i - 1792, mt = k / 128, r = k % 128, s = r / 64, lane = r % 64;
    int o = mt*16 + (lane & 15), q = lane >> 4, fi = mt*2 + s;
    #pragma unroll
    for (int j = 0; j < 8; ++j) {
      int c = s*32 + q*8 + j;
      float w = W2[o*64 + c];
      unsigned short hi = f2bf(w);
      unsigned short lo = f2bf(w - bf2f(hi));
      Apk2[((size_t)(fi)*64 + lane)*8 + j]        = hi;
      Apk2[((size_t)(16 + fi)*64 + lane)*8 + j]   = lo;
    }
  }
}

// ---------- KNN (R6-validated, DO NOT TOUCH: set-exact vs np top_k) ----------
__global__ __launch_bounds__(512) void k_knn(const float* __restrict__ pos1_re,
                                             const float4* __restrict__ pos2t,
                                             unsigned short* __restrict__ idxOut) {
  const int lane = threadIdx.x & 63;
  const int wv   = threadIdx.x >> 6;
  const int b = blockIdx.y;
  const int n = blockIdx.x * 8 + wv;

  const float qx = pos1_re[(b*3 + 0)*NN + n];
  const float qy = pos1_re[(b*3 + 1)*NN + n];
  const float qz = pos1_re[(b*3 + 2)*NN + n];
  const float q2 = __fadd_rn(__fadd_rn(__fmul_rn(qx,qx), __fmul_rn(qy,qy)), __fmul_rn(qz,qz));

  unsigned bd  = 0xFFFFFFFFu;
  unsigned bix = 0u;
  unsigned tau = 0xFFFFFFFFu;

  const float4* rp = pos2t + (size_t)b*NN;
  for (int it = 0; it < 64; ++it) {
    float4 r = rp[it*64 + lane];
    float dot = __fadd_rn(__fadd_rn(__fmul_rn(qx,r.x), __fmul_rn(qy,r.y)), __fmul_rn(qz,r.z));
    float d   = __fsub_rn(__fadd_rn(q2, r.w), __fmul_rn(2.0f, dot));
    unsigned du = __float_as_uint(d);
    du ^= (du >> 31) ? 0xFFFFFFFFu : 0x80000000u;

    unsigned long long mask = __ballot(du < tau);
    while (mask) {
      const int l = __ffsll((unsigned long long)mask) - 1;
      mask &= (mask - 1);
      const unsigned sd = (unsigned)__builtin_amdgcn_readlane((int)du, l);
      if (sd >= tau) continue;
      const unsigned sidx = (unsigned)(it*64 + l);
      int m = (bd > sd) ? 1 : 0;
      int pm = __builtin_amdgcn_update_dpp(0, m, 0x111, 0xF, 0xF, true);
      unsigned sb = (unsigned)__builtin_amdgcn_update_dpp(0, (int)bd,  0x111, 0xF, 0xF, true);
      unsigned si = (unsigned)__builtin_amdgcn_update_dpp(0, (int)bix, 0x111, 0xF, 0xF, true);
      if (m) { bd = pm ? sb : sd; bix = pm ? si : sidx; }
      tau = (unsigned)__builtin_amdgcn_readlane((int)bd, 15);
    }
  }

  if (lane < 16) {
    idxOut[((size_t)(b*NN + n))*KK + lane] = (unsigned short)bix;
  }
}

// ---------- wave-level deferred stat reduce (once per wave) ----------
#define WAVE_STATS(NMT) { \
  _Pragma("unroll") \
  for (int mt = 0; mt < NMT; ++mt) { \
    _Pragma("unroll") \
    for (int rg = 0; rg < 4; ++rg) { \
      float s_ = sacc[mt][rg], q_ = sqacc[mt][rg]; \
      s_ += __shfl_xor(s_,1); s_ += __shfl_xor(s_,2); s_ += __shfl_xor(s_,4); s_ += __shfl_xor(s_,8); \
      q_ += __shfl_xor(q_,1); q_ += __shfl_xor(q_,2); q_ += __shfl_xor(q_,4); q_ += __shfl_xor(q_,8); \
      if (cl == 0) { atomicAdd(&sS[mt*16 + q*4 + rg], s_); atomicAdd(&sQ[mt*16 + q*4 + rg], q_); } \
    } \
  } }

// ---------- layer 0: gather -> MFMA(64 x 160K) -> Y0 + stats; 32 pts/block ----------
__global__ __launch_bounds__(256) void k_layer0(
    const unsigned short* __restrict__ nidx, const float4* __restrict__ pos2t,
    const float* __restrict__ pos1, const unsigned short* __restrict__ f2b,
    const unsigned short* __restrict__ f1b, const unsigned short* __restrict__ Apk0,
    unsigned short* __restrict__ Y0, float* __restrict__ gS, float* __restrict__ gQ) {
  __shared__ __align__(16) unsigned short Wf[2*20*64*8];   // 40 KB
  __shared__ __align__(16) unsigned short Xs[4*16*168];    // 21504 B (pitch 168: 84dw%32=20 -> 2-way)
  __shared__ unsigned short idxL[4*8*16];                  // 1 KB
  __shared__ float sS[64], sQ[64];

  const int t = threadIdx.x, lane = t & 63, wv = t >> 6;
  const int b = blockIdx.y, n0 = blockIdx.x*32 + wv*8;
  const int cl = lane & 15, q = lane >> 4;

  for (int i = t; i < 2560; i += 256) ((short8*)Wf)[i] = ((const short8*)Apk0)[i];
  if (t < 64) { sS[t] = 0.f; sQ[t] = 0.f; }
  if (lane < 32)
    *(ushort4*)(idxL + wv*128 + lane*4) =
      *(const ushort4*)(nidx + ((size_t)(b*NN + n0))*KK + lane*4);
  __syncthreads();

  unsigned short* Xw = Xs + wv*16*168;
  f32x4 sacc[4]  = {{0,0,0,0},{0,0,0,0},{0,0,0,0},{0,0,0,0}};
  f32x4 sqacc[4] = {{0,0,0,0},{0,0,0,0},{0,0,0,0},{0,0,0,0}};

  #pragma unroll 1
  for (int p = 0; p < 8; ++p) {
    const int n = n0 + p;
    if (lane < 16) {
      int m = (int)idxL[wv*128 + p*16 + lane];
      float4 pp = pos2t[(size_t)b*NN + m];
      float px = pos1[(b*3 + 0)*NN + n];
      float py = pos1[(b*3 + 1)*NN + n];
      float pz = pos1[(b*3 + 2)*NN + n];
      ushort4 pd; pd.x = f2bf(pp.x - px); pd.y = f2bf(pp.y - py); pd.z = f2bf(pp.z - pz); pd.w = 0;
      *(ushort4*)(Xw + lane*168 + 128) = pd;
      ushort4 z4 = {0,0,0,0};
      *(ushort4*)(Xw + lane*168 + 132) = z4;
      short8 z8 = {0,0,0,0,0,0,0,0};
      *(short8*)(Xw + lane*168 + 136) = z8;
      *(short8*)(Xw + lane*168 + 144) = z8;
      *(short8*)(Xw + lane*168 + 152) = z8;
    }
    #pragma unroll
    for (int p2 = 0; p2 < 2; ++p2) {
      int kp = (lane >> 3) + p2*8, chunk = lane & 7;
      int m2 = (int)idxL[wv*128 + p*16 + kp];
      short8 v2 = *(const short8*)(f2b + ((size_t)(b*NN + m2))*64 + chunk*8);
      *(short8*)(Xw + kp*168 + chunk*8) = v2;
      short8 v1 = *(const short8*)(f1b + ((size_t)(b*NN + n))*64 + chunk*8);
      *(short8*)(Xw + kp*168 + 64 + chunk*8) = v1;
    }
    f32x4 acc[4] = {{0,0,0,0},{0,0,0,0},{0,0,0,0},{0,0,0,0}};
    #pragma unroll
    for (int s = 0; s < 5; ++s) {
      short8 bf = *(const short8*)(Xw + cl*168 + s*32 + q*8);
      #pragma unroll
      for (int mt = 0; mt < 4; ++mt) {
        short8 ah = *(const short8*)(Wf + ((mt*5 + s)*64 + lane)*8);
        short8 al = *(const short8*)(Wf + ((20 + mt*5 + s)*64 + lane)*8);
        acc[mt] = MFMA(ah, bf, acc[mt]);
        acc[mt] = MFMA(al, bf, acc[mt]);
      }
    }
    #pragma unroll
    for (int mt = 0; mt < 4; ++mt) {
      sacc[mt]  += acc[mt];
      sqacc[mt] += acc[mt]*acc[mt];
      ushort4 pk; pk.x = f2bf(acc[mt][0]); pk.y = f2bf(acc[mt][1]);
      pk.z = f2bf(acc[mt][2]); pk.w = f2bf(acc[mt][3]);
      *(ushort4*)(Xw + cl*168 + mt*16 + q*4) = pk;
    }
    #pragma unroll
    for (int p2 = 0; p2 < 2; ++p2) {
      int kp = (lane >> 3) + p2*8, chunk = lane & 7;
      short8 v = *(const short8*)(Xw + kp*168 + chunk*8);
      *(short8*)(Y0 + (((size_t)(b*NN + n))*KK + kp)*64 + chunk*8) = v;
    }
  }
  WAVE_STATS(4)
  __syncthreads();
  const int slot = blockIdx.x & 31;
  if (t < 64) { atomicAdd(&gS[slot*64 + t], sS[t]); atomicAdd(&gQ[slot*64 + t], sQ[t]); }
}

// ---------- finalize BN stats (sum 32 copies) ----------
__global__ __launch_bounds__(128) void k_finalize(const float* __restrict__ S, const float* __restrict__ Q,
                                                  const float* __restrict__ g, const float* __restrict__ bb_,
                                                  float* __restrict__ A, float* __restrict__ Bt, int ch) {
  int t = threadIdx.x;
  if (t < ch) {
    float s = 0.f, qq = 0.f;
    for (int c = 0; c < 32; ++c) { s += S[c*ch + t]; qq += Q[c*ch + t]; }
    float mean = s * (1.0f / NPOSF);
    float var  = qq * (1.0f / NPOSF) - mean*mean;
    float rs   = 1.0f / sqrtf(var + BNEPS);
    float a    = g[t] * rs;
    A[t] = a; Bt[t] = bb_[t] - mean*a;
  }
}

// ---------- layer 1: bn0+relu(Y0) -> MFMA(64x64) -> Y1 + stats; 32 pts/block ----------
__global__ __launch_bounds__(256) void k_layer1(
    const unsigned short* __restrict__ Y0, const float* __restrict__ A0, const float* __restrict__ B0,
    const unsigned short* __restrict__ Apk1, unsigned short* __restrict__ Y1,
    float* __restrict__ gS, float* __restrict__ gQ) {
  __shared__ __align__(16) unsigned short Wf[2*8*64*8];    // 16 KB
  __shared__ __align__(16) unsigned short Xs[4*16*72];     // 9216 B (pitch 72: 36dw%32=4 -> 2-way)
  __shared__ float aLs[64], bLs[64], sS[64], sQ[64];

  const int t = threadIdx.x, lane = t & 63, wv = t >> 6;
  const int b = blockIdx.y, n0 = blockIdx.x*32 + wv*8;
  const int cl = lane & 15, q = lane >> 4;

  for (int i = t; i < 1024; i += 256) ((short8*)Wf)[i] = ((const short8*)Apk1)[i];
  if (t < 64) { aLs[t] = A0[t]; bLs[t] = B0[t]; sS[t] = 0.f; sQ[t] = 0.f; }
  __syncthreads();

  unsigned short* Xw = Xs + wv*16*72;
  f32x4 sacc[4]  = {{0,0,0,0},{0,0,0,0},{0,0,0,0},{0,0,0,0}};
  f32x4 sqacc[4] = {{0,0,0,0},{0,0,0,0},{0,0,0,0},{0,0,0,0}};

  #pragma unroll 1
  for (int p = 0; p < 8; ++p) {
    const int n = n0 + p;
    const unsigned short* yrow = Y0 + ((size_t)(b*NN + n))*KK*64;
    #pragma unroll
    for (int p2 = 0; p2 < 2; ++p2) {
      int kp = (lane >> 3) + p2*8, chunk = lane & 7;
      short8 u = *(const short8*)(yrow + kp*64 + chunk*8);
      short8 xv;
      #pragma unroll
      for (int j = 0; j < 8; ++j) {
        int c = chunk*8 + j;
        float x = fmaxf(bf2f((unsigned short)u[j])*aLs[c] + bLs[c], 0.f);
        xv[j] = (short)f2bf(x);
      }
      *(short8*)(Xw + kp*72 + chunk*8) = xv;
    }
    f32x4 acc[4] = {{0,0,0,0},{0,0,0,0},{0,0,0,0},{0,0,0,0}};
    #pragma unroll
    for (int s = 0; s < 2; ++s) {
      short8 bf = *(const short8*)(Xw + cl*72 + s*32 + q*8);
      #pragma unroll
      for (int mt = 0; mt < 4; ++mt) {
        short8 ah = *(const short8*)(Wf + ((mt*2 + s)*64 + lane)*8);
        short8 al = *(const short8*)(Wf + ((8 + mt*2 + s)*64 + lane)*8);
        acc[mt] = MFMA(ah, bf, acc[mt]);
        acc[mt] = MFMA(al, bf, acc[mt]);
      }
    }
    #pragma unroll
    for (int mt = 0; mt < 4; ++mt) {
      sacc[mt]  += acc[mt];
      sqacc[mt] += acc[mt]*acc[mt];
      ushort4 pk; pk.x = f2bf(acc[mt][0]); pk.y = f2bf(acc[mt][1]);
      pk.z = f2bf(acc[mt][2]); pk.w = f2bf(acc[mt][3]);
      *(ushort4*)(Xw + cl*72 + mt*16 + q*4) = pk;
    }
    #pragma unroll
    for (int p2 = 0; p2 < 2; ++p2) {
      int kp = (lane >> 3) + p2*8, chunk = lane & 7;
      short8 v = *(const short8*)(Xw + kp*72 + chunk*8);
      *(short8*)(Y1 + (((size_t)(b*NN + n))*KK + kp)*64 + chunk*8) = v;
    }
  }
  WAVE_STATS(4)
  __syncthreads();
  const int slot = blockIdx.x & 31;
  if (t < 64) { atomicAdd(&gS[slot*64 + t], sS[t]); atomicAdd(&gQ[slot*64 + t], sQ[t]); }
}

// ---------- layer 2 stats: bn1+relu(Y1) -> MFMA(128x64) -> stats; 32 pts/block ----------
__global__ __launch_bounds__(256) void k_l2stats(
    const unsigned short* __restrict__ Y1, const float* __restrict__ A1, const float* __restrict__ B1,
    const unsigned short* __restrict__ Apk2, float* __restrict__ gS, float* __restrict__ gQ) {
  __shared__ __align__(16) unsigned short Wf[2*16*64*8];   // 32 KB
  __shared__ __align__(16) unsigned short Xs[4*16*72];     // 9216 B
  __shared__ float aLs[64], bLs[64];
  __shared__ float sS[128], sQ[128];

  const int t = threadIdx.x, lane = t & 63, wv = t >> 6;
  const int b = blockIdx.y, n0 = blockIdx.x*32 + wv*8;
  const int cl = lane & 15, q = lane >> 4;

  for (int i = t; i < 2048; i += 256) ((short8*)Wf)[i] = ((const short8*)Apk2)[i];
  if (t < 64) { aLs[t] = A1[t]; bLs[t] = B1[t]; }
  if (t < 128) { sS[t] = 0.f; sQ[t] = 0.f; }
  __syncthreads();

  unsigned short* Xw = Xs + wv*16*72;
  f32x4 sacc[8]  = {{0,0,0,0},{0,0,0,0},{0,0,0,0},{0,0,0,0},{0,0,0,0},{0,0,0,0},{0,0,0,0},{0,0,0,0}};
  f32x4 sqacc[8] = {{0,0,0,0},{0,0,0,0},{0,0,0,0},{0,0,0,0},{0,0,0,0},{0,0,0,0},{0,0,0,0},{0,0,0,0}};

  #pragma unroll 1
  for (int p = 0; p < 8; ++p) {
    const int n = n0 + p;
    const unsigned short* yrow = Y1 + ((size_t)(b*NN + n))*KK*64;
    #pragma unroll
    for (int p2 = 0; p2 < 2; ++p2) {
      int kp = (lane >> 3) + p2*8, chunk = lane & 7;
      short8 u = *(const short8*)(yrow + kp*64 + chunk*8);
      short8 xv;
      #pragma unroll
      for (int j = 0; j < 8; ++j) {
        int c = chunk*8 + j;
        float x = fmaxf(bf2f((unsigned short)u[j])*aLs[c] + bLs[c], 0.f);
        xv[j] = (short)f2bf(x);
      }
      *(short8*)(Xw + kp*72 + chunk*8) = xv;
    }
    f32x4 acc[8] = {{0,0,0,0},{0,0,0,0},{0,0,0,0},{0,0,0,0},{0,0,0,0},{0,0,0,0},{0,0,0,0},{0,0,0,0}};
    #pragma unroll
    for (int s = 0; s < 2; ++s) {
      short8 bf = *(const short8*)(Xw + cl*72 + s*32 + q*8);
      #pragma unroll
      for (int mt = 0; mt < 8; ++mt) {
        short8 ah = *(const short8*)(Wf + ((mt*2 + s)*64 + lane)*8);
        short8 al = *(const short8*)(Wf + ((16 + mt*2 + s)*64 + lane)*8);
        acc[mt] = MFMA(ah, bf, acc[mt]);
        acc[mt] = MFMA(al, bf, acc[mt]);
      }
    }
    #pragma unroll
    for (int mt = 0; mt < 8; ++mt) {
      sacc[mt]  += acc[mt];
      sqacc[mt] += acc[mt]*acc[mt];
    }
  }
  WAVE_STATS(8)
  __syncthreads();
  const int slot = blockIdx.x & 31;
  if (t < 128) { atomicAdd(&gS[slot*128 + t], sS[t]); atomicAdd(&gQ[slot*128 + t], sQ[t]); }
}

// ---------- layer 2 final: recompute y2, bn2+relu+max over k -> out; 32 pts/block ----------
__global__ __launch_bounds__(256) void k_l2final(
    const unsigned short* __restrict__ Y1, const float* __restrict__ A1, const float* __restrict__ B1,
    const unsigned short* __restrict__ Apk2, const float* __restrict__ A2, const float* __restrict__ B2,
    float* __restrict__ outF) {
  __shared__ __align__(16) unsigned short Wf[2*16*64*8];   // 32 KB
  __shared__ __align__(16) unsigned short Xs[4*16*72];     // 9216 B
  __shared__ float aLs[64], bLs[64];
  __shared__ float a2s[128], b2s[128];
  __shared__ float oBuf[32*128];                           // 16 KB [np][ch]

  const int t = threadIdx.x, lane = t & 63, wv = t >> 6;
  const int b = blockIdx.y, n0 = blockIdx.x*32 + wv*8;
  const int cl = lane & 15, q = lane >> 4;

  for (int i = t; i < 2048; i += 256) ((short8*)Wf)[i] = ((const short8*)Apk2)[i];
  if (t < 64) { aLs[t] = A1[t]; bLs[t] = B1[t]; }
  if (t < 128) { a2s[t] = A2[t]; b2s[t] = B2[t]; }
  __syncthreads();

  unsigned short* Xw = Xs + wv*16*72;

  #pragma unroll 1
  for (int p = 0; p < 8; ++p) {
    const int n = n0 + p;
    const unsigned short* yrow = Y1 + ((size_t)(b*NN + n))*KK*64;
    #pragma unroll
    for (int p2 = 0; p2 < 2; ++p2) {
      int kp = (lane >> 3) + p2*8, chunk = lane & 7;
      short8 u = *(const short8*)(yrow + kp*64 + chunk*8);
      short8 xv;
      #pragma unroll
      for (int j = 0; j < 8; ++j) {
        int c = chunk*8 + j;
        float x = fmaxf(bf2f((unsigned short)u[j])*aLs[c] + bLs[c], 0.f);
        xv[j] = (short)f2bf(x);
      }
      *(short8*)(Xw + kp*72 + chunk*8) = xv;
    }
    f32x4 acc[8] = {{0,0,0,0},{0,0,0,0},{0,0,0,0},{0,0,0,0},{0,0,0,0},{0,0,0,0},{0,0,0,0},{0,0,0,0}};
    #pragma unroll
    for (int s = 0; s < 2; ++s) {
      short8 bf = *(const short8*)(Xw + cl*72 + s*32 + q*8);
      #pragma unroll
      for (int mt = 0; mt < 8; ++mt) {
        short8 ah = *(const short8*)(Wf + ((mt*2 + s)*64 + lane)*8);
        short8 al = *(const short8*)(Wf + ((16 + mt*2 + s)*64 + lane)*8);
        acc[mt] = MFMA(ah, bf, acc[mt]);
        acc[mt] = MFMA(al, bf, acc[mt]);
      }
    }
    const int np = wv*8 + p;
    #pragma unroll
    for (int mt = 0; mt < 8; ++mt) {
      #pragma unroll
      for (int rg = 0; rg < 4; ++rg) {
        int ch = mt*16 + q*4 + rg;
        float v = fmaxf(acc[mt][rg]*a2s[ch] + b2s[ch], 0.f);
        v = fmaxf(v, __shfl_xor(v, 1));
        v = fmaxf(v, __shfl_xor(v, 2));
        v = fmaxf(v, __shfl_xor(v, 4));
        v = fmaxf(v, __shfl_xor(v, 8));
        if (cl == 0) oBuf[np*128 + ch] = v;
      }
    }
  }
  __syncthreads();
  {
    const int ch = t & 127, npb = (t >> 7) * 16;
    const int nb = blockIdx.x*32;
    #pragma unroll
    for (int g = 0; g < 4; ++g) {
      float4 v = make_float4(oBuf[(npb + g*4 + 0)*128 + ch],
                             oBuf[(npb + g*4 + 1)*128 + ch],
                             oBuf[(npb + g*4 + 2)*128 + ch],
                             oBuf[(npb + g*4 + 3)*128 + ch]);
      *(float4*)(outF + ((size_t)(b*H2 + ch))*NN + nb + npb + g*4) = v;
    }
  }
}

// ---------- launch ----------
extern "C" void kernel_launch(void* const* d_in, const int* in_sizes, int n_in,
                              void* d_out, int out_size, void* d_ws, size_t ws_size,
                              hipStream_t stream) {
  const float* pos1    = (const float*)d_in[0];
  const float* pos1_re = (const float*)d_in[1];
  const float* pos2    = (const float*)d_in[2];
  const float* f1      = (const float*)d_in[3];
  const float* f2      = (const float*)d_in[4];
  const float* W0 = (const float*)d_in[6];
  const float* g0 = (const float*)d_in[7];
  const float* b0 = (const float*)d_in[8];
  const float* W1 = (const float*)d_in[9];
  const float* g1 = (const float*)d_in[10];
  const float* b1 = (const float*)d_in[11];
  const float* W2 = (const float*)d_in[12];
  const float* g2 = (const float*)d_in[13];
  const float* b2 = (const float*)d_in[14];
  float* out = (float*)d_out;

  // workspace layout (bytes)
  char* ws = (char*)d_ws;
  float* stats = (float*)ws;                 // 65536 B
  float* S0 = stats;         float* Q0 = stats + 2048;
  float* S1 = stats + 4096;  float* Q1 = stats + 6144;
  float* S2 = stats + 8192;  float* Q2 = stats + 12288;
  float* prm = (float*)(ws + 65536);         // 2048 B
  float* A0 = prm;       float* B0a = prm + 64;
  float* A1 = prm + 128; float* B1a = prm + 192;
  float* A2 = prm + 256; float* B2a = prm + 384;
  unsigned short* Apk0 = (unsigned short*)(ws + 67584);    // 40960 B
  unsigned short* Apk1 = (unsigned short*)(ws + 108544);   // 16384 B
  unsigned short* Apk2 = (unsigned short*)(ws + 124928);   // 32768 B -> 157696
  unsigned short* idxb = (unsigned short*)(ws + 157696);   // 1 MB -> 1206272
  float4* pos2t        = (float4*)(ws + 1206272);          // 512 KB -> 1730560
  unsigned short* f2b  = (unsigned short*)(ws + 1730560);  // 4 MB -> 5924864
  unsigned short* f1b  = (unsigned short*)(ws + 5924864);  // 4 MB -> 10119168
  unsigned short* Y0   = (unsigned short*)(ws + 10119168); // 64 MB -> 77228032
  unsigned short* Y1   = (unsigned short*)(ws + 77228032); // 64 MB -> 144336896
  if (ws_size < 144336896u) return;

  k_zero<<<dim3(64), 256, 0, stream>>>(stats);
  k_wt<<<dim3(11), 256, 0, stream>>>(W0, W1, W2, Apk0, Apk1, Apk2);
  hipMemcpyAsync(out, pos1, (size_t)BB*3*NN*sizeof(float), hipMemcpyDeviceToDevice, stream);

  k_pos2t<<<dim3(BB*NN/256), 256, 0, stream>>>(pos2, pos2t);
  k_transposeb<<<dim3(NN/32, CC/32, BB), dim3(32, 8), 0, stream>>>(f2, f2b);
  k_transposeb<<<dim3(NN/32, CC/32, BB), dim3(32, 8), 0, stream>>>(f1, f1b);
  k_knn<<<dim3(NN/8, BB), 512, 0, stream>>>(pos1_re, pos2t, idxb);

  k_layer0<<<dim3(NN/32, BB), 256, 0, stream>>>(idxb, pos2t, pos1, f2b, f1b, Apk0, Y0, S0, Q0);
  k_finalize<<<1, 128, 0, stream>>>(S0, Q0, g0, b0, A0, B0a, 64);

  k_layer1<<<dim3(NN/32, BB), 256, 0, stream>>>(Y0, A0, B0a, Apk1, Y1, S1, Q1);
  k_finalize<<<1, 128, 0, stream>>>(S1, Q1, g1, b1, A1, B1a, 64);

  k_l2stats<<<dim3(NN/32, BB), 256, 0, stream>>>(Y1, A1, B1a, Apk2, S2, Q2);
  k_finalize<<<1, 128, 0, stream>>>(S2, Q2, g2, b2, A2, B2a, 128);

  k_l2final<<<dim3(NN/32, BB), 256, 0, stream>>>(Y1, A1, B1a, Apk2, A2, B2a, out + (size_t)BB*3*NN);
}

// Round 9
// 460.123 us; speedup vs baseline: 3.5114x; 1.3152x over previous
//
#include <hip/hip_runtime.h>
#include <hip/hip_bf16.h>
#include <cstdint>
#include <cstddef>

#define BB   8
#define NN   4096
#define CC   64
#define KK   16
#define H2   128
#define NPOSF 524288.0f
#define BNEPS 1e-5f

typedef __attribute__((ext_vector_type(8))) short  short8;
typedef __attribute__((ext_vector_type(4))) float  f32x4;

#define MFMA(a,b,c) __builtin_amdgcn_mfma_f32_16x16x32_bf16(a, b, c, 0, 0, 0)

// ---------- helpers ----------
__device__ __forceinline__ unsigned short f2bf(float x) {
  union { float f; unsigned u; } v; v.f = x;
  unsigned u = v.u;
  return (unsigned short)((u + 0x7fffu + ((u >> 16) & 1u)) >> 16);
}
__device__ __forceinline__ float bf2f(unsigned short h) {
  union { unsigned u; float f; } v; v.u = ((unsigned)h) << 16; return v.f;
}

// ---------- utility kernels ----------
__global__ __launch_bounds__(256) void k_zero(float* p) {
  p[blockIdx.x * 256 + threadIdx.x] = 0.f;
}

// pos2t[b][n] = (x,y,z, x^2+y^2+z^2) — PINNED to np rounding
__global__ __launch_bounds__(256) void k_pos2t(const float* __restrict__ pos2, float4* __restrict__ out) {
  int i = blockIdx.x * 256 + threadIdx.x;
  int b = i >> 12, n = i & 4095;
  float x = pos2[(b*3 + 0)*NN + n];
  float y = pos2[(b*3 + 1)*NN + n];
  float z = pos2[(b*3 + 2)*NN + n];
  float w = __fadd_rn(__fadd_rn(__fmul_rn(x,x), __fmul_rn(y,y)), __fmul_rn(z,z));
  out[i] = make_float4(x, y, z, w);
}

// [B,64,N] fp32 -> [B,N,64] bf16
__global__ __launch_bounds__(256) void k_transposeb(const float* __restrict__ in, unsigned short* __restrict__ out) {
  __shared__ float tile[32][33];
  int b = blockIdx.z;
  int n0 = blockIdx.x * 32, c0 = blockIdx.y * 32;
  int tx = threadIdx.x, ty = threadIdx.y;
  #pragma unroll
  for (int i = 0; i < 32; i += 8)
    tile[ty + i][tx] = in[((size_t)(b*CC + c0 + ty + i))*NN + n0 + tx];
  __syncthreads();
  #pragma unroll
  for (int i = 0; i < 32; i += 8)
    out[((size_t)(b*NN + n0 + ty + i))*CC + c0 + tx] = f2bf(tile[tx][ty + i]);
}

// ---------- weight pre-pack: A-fragment order (hi bf16) ----------
// A[m=lane&15][k=quad*8+j] per mfma_f32_16x16x32_bf16. Layer0 channel reorder:
// c'<128 -> orig c'+3 (f2 then f1), c'=128..130 -> pos_diff, pad->0.
__global__ __launch_bounds__(256) void k_wt(const float* __restrict__ W0, const float* __restrict__ W1,
                                            const float* __restrict__ W2, unsigned short* __restrict__ Apk0,
                                            unsigned short* __restrict__ Apk1, unsigned short* __restrict__ Apk2) {
  int i = blockIdx.x * 256 + threadIdx.x;
  if (i < 1280) {            // L0: 4 mt x 5 s x 64 lanes
    int mt = i / 320, r = i % 320, s = r / 64, lane = r % 64;
    int o = mt*16 + (lane & 15), q = lane >> 4, fi = mt*5 + s;
    #pragma unroll
    for (int j = 0; j < 8; ++j) {
      int c = s*32 + q*8 + j;
      float w = 0.f;
      if (c < 131) { int cs = (c < 128) ? (c + 3) : (c - 128); w = W0[o*131 + cs]; }
      Apk0[((size_t)(fi)*64 + lane)*8 + j] = f2bf(w);
    }
  } else if (i < 1792) {     // L1: 4 mt x 2 s
    int k = i - 1280, mt = k / 128, r = k % 128, s = r / 64, lane = r % 64;
    int o = mt*16 + (lane & 15), q = lane >> 4, fi = mt*2 + s;
    #pragma unroll
    for (int j = 0; j < 8; ++j) {
      int c = s*32 + q*8 + j;
      Apk1[((size_t)(fi)*64 + lane)*8 + j] = f2bf(W1[o*64 + c]);
    }
  } else if (i < 2816) {     // L2: 8 mt x 2 s
    int k = i - 1792, mt = k / 128, r = k % 128, s = r / 64, lane = r % 64;
    int o = mt*16 + (lane & 15), q = lane >> 4, fi = mt*2 + s;
    #pragma unroll
    for (int j = 0; j < 8; ++j) {
      int c = s*32 + q*8 + j;
      Apk2[((size_t)(fi)*64 + lane)*8 + j] = f2bf(W2[o*64 + c]);
    }
  }
}

// ---------- KNN (R6-validated, DO NOT TOUCH: set-exact vs np top_k) ----------
__global__ __launch_bounds__(512) void k_knn(const float* __restrict__ pos1_re,
                                             const float4* __restrict__ pos2t,
                                             unsigned short* __restrict__ idxOut) {
  const int lane = threadIdx.x & 63;
  const int wv   = threadIdx.x >> 6;
  const int b = blockIdx.y;
  const int n = blockIdx.x * 8 + wv;

  const float qx = pos1_re[(b*3 + 0)*NN + n];
  const float qy = pos1_re[(b*3 + 1)*NN + n];
  const float qz = pos1_re[(b*3 + 2)*NN + n];
  const float q2 = __fadd_rn(__fadd_rn(__fmul_rn(qx,qx), __fmul_rn(qy,qy)), __fmul_rn(qz,qz));

  unsigned bd  = 0xFFFFFFFFu;
  unsigned bix = 0u;
  unsigned tau = 0xFFFFFFFFu;

  const float4* rp = pos2t + (size_t)b*NN;
  for (int it = 0; it < 64; ++it) {
    float4 r = rp[it*64 + lane];
    float dot = __fadd_rn(__fadd_rn(__fmul_rn(qx,r.x), __fmul_rn(qy,r.y)), __fmul_rn(qz,r.z));
    float d   = __fsub_rn(__fadd_rn(q2, r.w), __fmul_rn(2.0f, dot));
    unsigned du = __float_as_uint(d);
    du ^= (du >> 31) ? 0xFFFFFFFFu : 0x80000000u;

    unsigned long long mask = __ballot(du < tau);
    while (mask) {
      const int l = __ffsll((unsigned long long)mask) - 1;
      mask &= (mask - 1);
      const unsigned sd = (unsigned)__builtin_amdgcn_readlane((int)du, l);
      if (sd >= tau) continue;
      const unsigned sidx = (unsigned)(it*64 + l);
      int m = (bd > sd) ? 1 : 0;
      int pm = __builtin_amdgcn_update_dpp(0, m, 0x111, 0xF, 0xF, true);
      unsigned sb = (unsigned)__builtin_amdgcn_update_dpp(0, (int)bd,  0x111, 0xF, 0xF, true);
      unsigned si = (unsigned)__builtin_amdgcn_update_dpp(0, (int)bix, 0x111, 0xF, 0xF, true);
      if (m) { bd = pm ? sb : sd; bix = pm ? si : sidx; }
      tau = (unsigned)__builtin_amdgcn_readlane((int)bd, 15);
    }
  }

  if (lane < 16) {
    idxOut[((size_t)(b*NN + n))*KK + lane] = (unsigned short)bix;
  }
}

// ---------- wave-level deferred stat reduce (once per wave) ----------
#define WAVE_STATS(NMT) { \
  _Pragma("unroll") \
  for (int mt = 0; mt < NMT; ++mt) { \
    _Pragma("unroll") \
    for (int rg = 0; rg < 4; ++rg) { \
      float s_ = sacc[mt][rg], q_ = sqacc[mt][rg]; \
      s_ += __shfl_xor(s_,1); s_ += __shfl_xor(s_,2); s_ += __shfl_xor(s_,4); s_ += __shfl_xor(s_,8); \
      q_ += __shfl_xor(q_,1); q_ += __shfl_xor(q_,2); q_ += __shfl_xor(q_,4); q_ += __shfl_xor(q_,8); \
      if (cl == 0) { atomicAdd(&sS[mt*16 + q*4 + rg], s_); atomicAdd(&sQ[mt*16 + q*4 + rg], q_); } \
    } \
  } }

// ---------- layer 0: gather -> MFMA(64 x 160K), reg weights, no LDS staging ----------
__global__ __launch_bounds__(256) void k_layer0(
    const unsigned short* __restrict__ nidx, const float4* __restrict__ pos2t,
    const float* __restrict__ pos1, const unsigned short* __restrict__ f2b,
    const unsigned short* __restrict__ f1b, const unsigned short* __restrict__ Apk0,
    unsigned short* __restrict__ Y0, float* __restrict__ gS, float* __restrict__ gQ) {
  __shared__ float sS[64], sQ[64];
  const int t = threadIdx.x, lane = t & 63, wv = t >> 6;
  const int b = blockIdx.y, n0 = blockIdx.x*32 + wv*8;
  const int cl = lane & 15, q = lane >> 4;

  short8 Wr[20];
  #pragma unroll
  for (int f = 0; f < 20; ++f) Wr[f] = *(const short8*)(Apk0 + ((size_t)f*64 + lane)*8);
  if (t < 64) { sS[t] = 0.f; sQ[t] = 0.f; }
  __syncthreads();

  f32x4 sacc[4]  = {{0,0,0,0},{0,0,0,0},{0,0,0,0},{0,0,0,0}};
  f32x4 sqacc[4] = {{0,0,0,0},{0,0,0,0},{0,0,0,0},{0,0,0,0}};

  #pragma unroll 1
  for (int p = 0; p < 8; ++p) {
    const int n = n0 + p;
    const int m = (int)nidx[((size_t)(b*NN + n))*KK + cl];
    const unsigned short* f2r = f2b + ((size_t)(b*NN + m))*64;
    const unsigned short* f1r = f1b + ((size_t)(b*NN + n))*64;
    short8 x0 = *(const short8*)(f2r + q*8);
    short8 x1 = *(const short8*)(f2r + 32 + q*8);
    short8 x2 = *(const short8*)(f1r + q*8);
    short8 x3 = *(const short8*)(f1r + 32 + q*8);
    short8 x4 = {0,0,0,0,0,0,0,0};
    if (q == 0) {
      float4 pp = pos2t[(size_t)b*NN + m];
      float px = pos1[(b*3 + 0)*NN + n];
      float py = pos1[(b*3 + 1)*NN + n];
      float pz = pos1[(b*3 + 2)*NN + n];
      x4[0] = (short)f2bf(pp.x - px);
      x4[1] = (short)f2bf(pp.y - py);
      x4[2] = (short)f2bf(pp.z - pz);
    }
    f32x4 acc[4] = {{0,0,0,0},{0,0,0,0},{0,0,0,0},{0,0,0,0}};
    #pragma unroll
    for (int mt = 0; mt < 4; ++mt) {
      acc[mt] = MFMA(Wr[mt*5 + 0], x0, acc[mt]);
      acc[mt] = MFMA(Wr[mt*5 + 1], x1, acc[mt]);
      acc[mt] = MFMA(Wr[mt*5 + 2], x2, acc[mt]);
      acc[mt] = MFMA(Wr[mt*5 + 3], x3, acc[mt]);
      acc[mt] = MFMA(Wr[mt*5 + 4], x4, acc[mt]);
    }
    unsigned short* yr = Y0 + (((size_t)(b*NN + n))*KK + cl)*64;
    #pragma unroll
    for (int mt = 0; mt < 4; ++mt) {
      sacc[mt]  += acc[mt];
      sqacc[mt] += acc[mt]*acc[mt];
      ushort4 pk; pk.x = f2bf(acc[mt][0]); pk.y = f2bf(acc[mt][1]);
      pk.z = f2bf(acc[mt][2]); pk.w = f2bf(acc[mt][3]);
      *(ushort4*)(yr + mt*16 + q*4) = pk;
    }
  }
  WAVE_STATS(4)
  __syncthreads();
  const int slot = blockIdx.x & 31;
  if (t < 64) { atomicAdd(&gS[slot*64 + t], sS[t]); atomicAdd(&gQ[slot*64 + t], sQ[t]); }
}

// ---------- finalize BN stats (sum 32 copies) ----------
__global__ __launch_bounds__(128) void k_finalize(const float* __restrict__ S, const float* __restrict__ Q,
                                                  const float* __restrict__ g, const float* __restrict__ bb_,
                                                  float* __restrict__ A, float* __restrict__ Bt, int ch) {
  int t = threadIdx.x;
  if (t < ch) {
    float s = 0.f, qq = 0.f;
    for (int c = 0; c < 32; ++c) { s += S[c*ch + t]; qq += Q[c*ch + t]; }
    float mean = s * (1.0f / NPOSF);
    float var  = qq * (1.0f / NPOSF) - mean*mean;
    float rs   = 1.0f / sqrtf(var + BNEPS);
    float a    = g[t] * rs;
    A[t] = a; Bt[t] = bb_[t] - mean*a;
  }
}

// ---------- layer 1: bn0+relu(Y0) -> MFMA(64x64), reg weights ----------
__global__ __launch_bounds__(256) void k_layer1(
    const unsigned short* __restrict__ Y0, const float* __restrict__ A0, const float* __restrict__ B0,
    const unsigned short* __restrict__ Apk1, unsigned short* __restrict__ Y1,
    float* __restrict__ gS, float* __restrict__ gQ) {
  __shared__ float sS[64], sQ[64];
  const int t = threadIdx.x, lane = t & 63, wv = t >> 6;
  const int b = blockIdx.y, n0 = blockIdx.x*32 + wv*8;
  const int cl = lane & 15, q = lane >> 4;

  short8 Wr[8];
  #pragma unroll
  for (int f = 0; f < 8; ++f) Wr[f] = *(const short8*)(Apk1 + ((size_t)f*64 + lane)*8);
  float ar[16], br[16];
  #pragma unroll
  for (int s = 0; s < 2; ++s)
    #pragma unroll
    for (int j = 0; j < 8; ++j) { int c = s*32 + q*8 + j; ar[s*8+j] = A0[c]; br[s*8+j] = B0[c]; }
  if (t < 64) { sS[t] = 0.f; sQ[t] = 0.f; }
  __syncthreads();

  f32x4 sacc[4]  = {{0,0,0,0},{0,0,0,0},{0,0,0,0},{0,0,0,0}};
  f32x4 sqacc[4] = {{0,0,0,0},{0,0,0,0},{0,0,0,0},{0,0,0,0}};

  #pragma unroll 1
  for (int p = 0; p < 8; ++p) {
    const int n = n0 + p;
    const unsigned short* yr = Y0 + (((size_t)(b*NN + n))*KK + cl)*64;
    short8 u0 = *(const short8*)(yr + q*8);
    short8 u1 = *(const short8*)(yr + 32 + q*8);
    short8 x0, x1;
    #pragma unroll
    for (int j = 0; j < 8; ++j) {
      x0[j] = (short)f2bf(fmaxf(bf2f((unsigned short)u0[j])*ar[j]   + br[j],   0.f));
      x1[j] = (short)f2bf(fmaxf(bf2f((unsigned short)u1[j])*ar[8+j] + br[8+j], 0.f));
    }
    f32x4 acc[4] = {{0,0,0,0},{0,0,0,0},{0,0,0,0},{0,0,0,0}};
    #pragma unroll
    for (int mt = 0; mt < 4; ++mt) {
      acc[mt] = MFMA(Wr[mt*2 + 0], x0, acc[mt]);
      acc[mt] = MFMA(Wr[mt*2 + 1], x1, acc[mt]);
    }
    unsigned short* yw = Y1 + (((size_t)(b*NN + n))*KK + cl)*64;
    #pragma unroll
    for (int mt = 0; mt < 4; ++mt) {
      sacc[mt]  += acc[mt];
      sqacc[mt] += acc[mt]*acc[mt];
      ushort4 pk; pk.x = f2bf(acc[mt][0]); pk.y = f2bf(acc[mt][1]);
      pk.z = f2bf(acc[mt][2]); pk.w = f2bf(acc[mt][3]);
      *(ushort4*)(yw + mt*16 + q*4) = pk;
    }
  }
  WAVE_STATS(4)
  __syncthreads();
  const int slot = blockIdx.x & 31;
  if (t < 64) { atomicAdd(&gS[slot*64 + t], sS[t]); atomicAdd(&gQ[slot*64 + t], sQ[t]); }
}

// ---------- layer 2 stats: bn1+relu(Y1) -> MFMA(128x64) -> stats ----------
__global__ __launch_bounds__(256) void k_l2stats(
    const unsigned short* __restrict__ Y1, const float* __restrict__ A1, const float* __restrict__ B1,
    const unsigned short* __restrict__ Apk2, float* __restrict__ gS, float* __restrict__ gQ) {
  __shared__ float sS[128], sQ[128];
  const int t = threadIdx.x, lane = t & 63, wv = t >> 6;
  const int b = blockIdx.y, n0 = blockIdx.x*32 + wv*8;
  const int cl = lane & 15, q = lane >> 4;

  short8 Wr[16];
  #pragma unroll
  for (int f = 0; f < 16; ++f) Wr[f] = *(const short8*)(Apk2 + ((size_t)f*64 + lane)*8);
  float ar[16], br[16];
  #pragma unroll
  for (int s = 0; s < 2; ++s)
    #pragma unroll
    for (int j = 0; j < 8; ++j) { int c = s*32 + q*8 + j; ar[s*8+j] = A1[c]; br[s*8+j] = B1[c]; }
  if (t < 128) { sS[t] = 0.f; sQ[t] = 0.f; }
  __syncthreads();

  f32x4 sacc[8]  = {{0,0,0,0},{0,0,0,0},{0,0,0,0},{0,0,0,0},{0,0,0,0},{0,0,0,0},{0,0,0,0},{0,0,0,0}};
  f32x4 sqacc[8] = {{0,0,0,0},{0,0,0,0},{0,0,0,0},{0,0,0,0},{0,0,0,0},{0,0,0,0},{0,0,0,0},{0,0,0,0}};

  #pragma unroll 1
  for (int p = 0; p < 8; ++p) {
    const int n = n0 + p;
    const unsigned short* yr = Y1 + (((size_t)(b*NN + n))*KK + cl)*64;
    short8 u0 = *(const short8*)(yr + q*8);
    short8 u1 = *(const short8*)(yr + 32 + q*8);
    short8 x0, x1;
    #pragma unroll
    for (int j = 0; j < 8; ++j) {
      x0[j] = (short)f2bf(fmaxf(bf2f((unsigned short)u0[j])*ar[j]   + br[j],   0.f));
      x1[j] = (short)f2bf(fmaxf(bf2f((unsigned short)u1[j])*ar[8+j] + br[8+j], 0.f));
    }
    #pragma unroll
    for (int mt = 0; mt < 8; ++mt) {
      f32x4 acc = {0,0,0,0};
      acc = MFMA(Wr[mt*2 + 0], x0, acc);
      acc = MFMA(Wr[mt*2 + 1], x1, acc);
      sacc[mt]  += acc;
      sqacc[mt] += acc*acc;
    }
  }
  WAVE_STATS(8)
  __syncthreads();
  const int slot = blockIdx.x & 31;
  if (t < 128) { atomicAdd(&gS[slot*128 + t], sS[t]); atomicAdd(&gQ[slot*128 + t], sQ[t]); }
}

// ---------- layer 2 final: recompute y2, bn2+relu+max over k -> out ----------
__global__ __launch_bounds__(256) void k_l2final(
    const unsigned short* __restrict__ Y1, const float* __restrict__ A1, const float* __restrict__ B1,
    const unsigned short* __restrict__ Apk2, const float* __restrict__ A2, const float* __restrict__ B2,
    float* __restrict__ outF) {
  __shared__ float a2s[128], b2s[128];
  __shared__ float oBuf[32*128];                           // 16 KB [np][ch]
  const int t = threadIdx.x, lane = t & 63, wv = t >> 6;
  const int b = blockIdx.y, n0 = blockIdx.x*32 + wv*8;
  const int cl = lane & 15, q = lane >> 4;

  short8 Wr[16];
  #pragma unroll
  for (int f = 0; f < 16; ++f) Wr[f] = *(const short8*)(Apk2 + ((size_t)f*64 + lane)*8);
  float ar[16], br[16];
  #pragma unroll
  for (int s = 0; s < 2; ++s)
    #pragma unroll
    for (int j = 0; j < 8; ++j) { int c = s*32 + q*8 + j; ar[s*8+j] = A1[c]; br[s*8+j] = B1[c]; }
  if (t < 128) { a2s[t] = A2[t]; b2s[t] = B2[t]; }
  __syncthreads();

  #pragma unroll 1
  for (int p = 0; p < 8; ++p) {
    const int n = n0 + p;
    const unsigned short* yr = Y1 + (((size_t)(b*NN + n))*KK + cl)*64;
    short8 u0 = *(const short8*)(yr + q*8);
    short8 u1 = *(const short8*)(yr + 32 + q*8);
    short8 x0, x1;
    #pragma unroll
    for (int j = 0; j < 8; ++j) {
      x0[j] = (short)f2bf(fmaxf(bf2f((unsigned short)u0[j])*ar[j]   + br[j],   0.f));
      x1[j] = (short)f2bf(fmaxf(bf2f((unsigned short)u1[j])*ar[8+j] + br[8+j], 0.f));
    }
    const int np = wv*8 + p;
    #pragma unroll
    for (int mt = 0; mt < 8; ++mt) {
      f32x4 acc = {0,0,0,0};
      acc = MFMA(Wr[mt*2 + 0], x0, acc);
      acc = MFMA(Wr[mt*2 + 1], x1, acc);
      #pragma unroll
      for (int rg = 0; rg < 4; ++rg) {
        int ch = mt*16 + q*4 + rg;
        float v = fmaxf(acc[rg]*a2s[ch] + b2s[ch], 0.f);
        v = fmaxf(v, __shfl_xor(v, 1));
        v = fmaxf(v, __shfl_xor(v, 2));
        v = fmaxf(v, __shfl_xor(v, 4));
        v = fmaxf(v, __shfl_xor(v, 8));
        if (cl == 0) oBuf[np*128 + ch] = v;
      }
    }
  }
  __syncthreads();
  {
    const int ch = t & 127, npb = (t >> 7) * 16;
    const int nb = blockIdx.x*32;
    #pragma unroll
    for (int g = 0; g < 4; ++g) {
      float4 v = make_float4(oBuf[(npb + g*4 + 0)*128 + ch],
                             oBuf[(npb + g*4 + 1)*128 + ch],
                             oBuf[(npb + g*4 + 2)*128 + ch],
                             oBuf[(npb + g*4 + 3)*128 + ch]);
      *(float4*)(outF + ((size_t)(b*H2 + ch))*NN + nb + npb + g*4) = v;
    }
  }
}

// ---------- launch ----------
extern "C" void kernel_launch(void* const* d_in, const int* in_sizes, int n_in,
                              void* d_out, int out_size, void* d_ws, size_t ws_size,
                              hipStream_t stream) {
  const float* pos1    = (const float*)d_in[0];
  const float* pos1_re = (const float*)d_in[1];
  const float* pos2    = (const float*)d_in[2];
  const float* f1      = (const float*)d_in[3];
  const float* f2      = (const float*)d_in[4];
  const float* W0 = (const float*)d_in[6];
  const float* g0 = (const float*)d_in[7];
  const float* b0 = (const float*)d_in[8];
  const float* W1 = (const float*)d_in[9];
  const float* g1 = (const float*)d_in[10];
  const float* b1 = (const float*)d_in[11];
  const float* W2 = (const float*)d_in[12];
  const float* g2 = (const float*)d_in[13];
  const float* b2 = (const float*)d_in[14];
  float* out = (float*)d_out;

  // workspace layout (bytes)
  char* ws = (char*)d_ws;
  float* stats = (float*)ws;                 // 65536 B
  float* S0 = stats;         float* Q0 = stats + 2048;
  float* S1 = stats + 4096;  float* Q1 = stats + 6144;
  float* S2 = stats + 8192;  float* Q2 = stats + 12288;
  float* prm = (float*)(ws + 65536);         // 2048 B
  float* A0 = prm;       float* B0a = prm + 64;
  float* A1 = prm + 128; float* B1a = prm + 192;
  float* A2 = prm + 256; float* B2a = prm + 384;
  unsigned short* Apk0 = (unsigned short*)(ws + 67584);    // 20480 B (hi only used)
  unsigned short* Apk1 = (unsigned short*)(ws + 108544);   // 8192 B used
  unsigned short* Apk2 = (unsigned short*)(ws + 124928);   // 16384 B used
  unsigned short* idxb = (unsigned short*)(ws + 157696);   // 1 MB
  float4* pos2t        = (float4*)(ws + 1206272);          // 512 KB
  unsigned short* f2b  = (unsigned short*)(ws + 1730560);  // 4 MB
  unsigned short* f1b  = (unsigned short*)(ws + 5924864);  // 4 MB
  unsigned short* Y0   = (unsigned short*)(ws + 10119168); // 64 MB
  unsigned short* Y1   = (unsigned short*)(ws + 77228032); // 64 MB -> 144336896
  if (ws_size < 144336896u) return;

  k_zero<<<dim3(64), 256, 0, stream>>>(stats);
  k_wt<<<dim3(11), 256, 0, stream>>>(W0, W1, W2, Apk0, Apk1, Apk2);
  hipMemcpyAsync(out, pos1, (size_t)BB*3*NN*sizeof(float), hipMemcpyDeviceToDevice, stream);

  k_pos2t<<<dim3(BB*NN/256), 256, 0, stream>>>(pos2, pos2t);
  k_transposeb<<<dim3(NN/32, CC/32, BB), dim3(32, 8), 0, stream>>>(f2, f2b);
  k_transposeb<<<dim3(NN/32, CC/32, BB), dim3(32, 8), 0, stream>>>(f1, f1b);
  k_knn<<<dim3(NN/8, BB), 512, 0, stream>>>(pos1_re, pos2t, idxb);

  k_layer0<<<dim3(NN/32, BB), 256, 0, stream>>>(idxb, pos2t, pos1, f2b, f1b, Apk0, Y0, S0, Q0);
  k_finalize<<<1, 128, 0, stream>>>(S0, Q0, g0, b0, A0, B0a, 64);

  k_layer1<<<dim3(NN/32, BB), 256, 0, stream>>>(Y0, A0, B0a, Apk1, Y1, S1, Q1);
  k_finalize<<<1, 128, 0, stream>>>(S1, Q1, g1, b1, A1, B1a, 64);

  k_l2stats<<<dim3(NN/32, BB), 256, 0, stream>>>(Y1, A1, B1a, Apk2, S2, Q2);
  k_finalize<<<1, 128, 0, stream>>>(S2, Q2, g2, b2, A2, B2a, 128);

  k_l2final<<<dim3(NN/32, BB), 256, 0, stream>>>(Y1, A1, B1a, Apk2, A2, B2a, out + (size_t)BB*3*NN);
}